// Round 1
// baseline (5075.441 us; speedup 1.0000x reference)
//
#include <hip/hip_runtime.h>

#define NNODES 200000
#define NEDGES 400000
#define NGRAPH 8000
#define ADIM 100
#define HDIM 128
#define NLAYER 4

typedef float4 f4;

__device__ __forceinline__ float relu_f(float x) { return fmaxf(x, 0.0f); }

// ---------------------------------------------------------------------------
// GEMM: C[N,128] = f(A)[N,K] @ W[K,128] (+bias); optional column stats of C.
// One block = 64 rows x full 128 cols  ->  in-place (C==A) is safe.
// f(A) = optional per-input-column scale/shift + ReLU (applies previous BN).
// ---------------------------------------------------------------------------
template <int K, int PA, bool SSRELU, bool STATS>
__global__ __launch_bounds__(256, 1) void gemm_fused(
    const float* __restrict__ A, const float* __restrict__ W,
    const float* __restrict__ bias, const float* __restrict__ ssin,
    float* __restrict__ C, float* __restrict__ stats)
{
    __shared__ float Wl[K * HDIM];
    __shared__ float Al[64 * PA];
    __shared__ float red[STATS ? 16 * 130 : 1];

    const int t = threadIdx.x;
    const long row0 = (long)blockIdx.x * 64;

    // stage W [K][128]
    for (int idx = t; idx < K * (HDIM / 4); idx += 256) {
        int k = idx >> 5;
        int c4 = (idx & 31) << 2;
        *(f4*)&Wl[k * HDIM + c4] = *(const f4*)&W[k * HDIM + c4];
    }
    // stage A tile [64][K] (padded pitch PA), optional scale/shift+relu
    for (int idx = t; idx < 64 * (K / 4); idx += 256) {
        int r = idx / (K / 4);
        int c4 = (idx % (K / 4)) << 2;
        f4 a = *(const f4*)&A[(row0 + r) * K + c4];
        if (SSRELU) {
            f4 sc = *(const f4*)&ssin[c4];
            f4 sh = *(const f4*)&ssin[K + c4];
            a.x = relu_f(fmaf(a.x, sc.x, sh.x));
            a.y = relu_f(fmaf(a.y, sc.y, sh.y));
            a.z = relu_f(fmaf(a.z, sc.z, sh.z));
            a.w = relu_f(fmaf(a.w, sc.w, sh.w));
        }
        float* p = &Al[r * PA + c4];
        p[0] = a.x; p[1] = a.y; p[2] = a.z; p[3] = a.w;
    }
    __syncthreads();

    const int tr = t & 15;   // 4 rows each
    const int tc = t >> 4;   // 8 cols each

    float acc[4][8];
#pragma unroll
    for (int i = 0; i < 4; ++i)
#pragma unroll
        for (int j = 0; j < 8; ++j) acc[i][j] = 0.0f;

#pragma unroll 4
    for (int k = 0; k < K; ++k) {
        float av[4];
#pragma unroll
        for (int i = 0; i < 4; ++i) av[i] = Al[(4 * tr + i) * PA + k];
        float bv[8];
        *(f4*)&bv[0] = *(const f4*)&Wl[k * HDIM + 8 * tc];
        *(f4*)&bv[4] = *(const f4*)&Wl[k * HDIM + 8 * tc + 4];
#pragma unroll
        for (int i = 0; i < 4; ++i)
#pragma unroll
            for (int j = 0; j < 8; ++j) acc[i][j] = fmaf(av[i], bv[j], acc[i][j]);
    }

    float bv[8] = {0, 0, 0, 0, 0, 0, 0, 0};
    if (STATS) {
        *(f4*)&bv[0] = *(const f4*)&bias[8 * tc];
        *(f4*)&bv[4] = *(const f4*)&bias[8 * tc + 4];
    }
    float psum[8] = {0, 0, 0, 0, 0, 0, 0, 0};
    float psq[8] = {0, 0, 0, 0, 0, 0, 0, 0};
#pragma unroll
    for (int i = 0; i < 4; ++i) {
        float outv[8];
#pragma unroll
        for (int j = 0; j < 8; ++j) {
            float val = acc[i][j] + bv[j];
            outv[j] = val;
            if (STATS) { psum[j] += val; psq[j] += val * val; }
        }
        long row = row0 + 4 * tr + i;
        *(f4*)&C[row * HDIM + 8 * tc] = *(f4*)&outv[0];
        *(f4*)&C[row * HDIM + 8 * tc + 4] = *(f4*)&outv[4];
    }

    if (STATS) {
#pragma unroll
        for (int j = 0; j < 8; ++j) red[tr * 130 + 8 * tc + j] = psum[j];
        __syncthreads();
        if (t < HDIM) {
            float s = 0;
#pragma unroll
            for (int r = 0; r < 16; ++r) s += red[r * 130 + t];
            atomicAdd(&stats[t], s);
        }
        __syncthreads();
#pragma unroll
        for (int j = 0; j < 8; ++j) red[tr * 130 + 8 * tc + j] = psq[j];
        __syncthreads();
        if (t < HDIM) {
            float s = 0;
#pragma unroll
            for (int r = 0; r < 16; ++r) s += red[r * 130 + t];
            atomicAdd(&stats[HDIM + t], s);
        }
    }
}

// P[n] = (1+eps)*h[n]
__global__ void build_x(const float* __restrict__ Hc, const float* __restrict__ eps_gin,
                        int layer, float* __restrict__ P)
{
    size_t i = (size_t)blockIdx.x * 256 + threadIdx.x;  // float4 index
    float s = 1.0f + eps_gin[layer];
    f4 v = ((const f4*)Hc)[i];
    v.x *= s; v.y *= s; v.z *= s; v.w *= s;
    ((f4*)P)[i] = v;
}

// P[dst[e]] += H[src[e]]  (32 threads per edge, 4 floats each)
__global__ void scatter_add(const float* __restrict__ H, const int* __restrict__ src,
                            const int* __restrict__ dst, float* __restrict__ P)
{
    int t = blockIdx.x * 256 + threadIdx.x;
    int e = t >> 5;
    int j = (t & 31) << 2;
    int s = src[e], d = dst[e];
    f4 v = *(const f4*)&H[(size_t)s * HDIM + j];
    float* p = &P[(size_t)d * HDIM + j];
    atomicAdd(p + 0, v.x);
    atomicAdd(p + 1, v.y);
    atomicAdd(p + 2, v.z);
    atomicAdd(p + 3, v.w);
}

// P = relu(P*sc+sh) * snorm (in place), stats of result
__global__ __launch_bounds__(256) void x3_kernel(float* __restrict__ P,
                                                 const float* __restrict__ ss,
                                                 const float* __restrict__ snorm,
                                                 float* __restrict__ stats)
{
    __shared__ float red[8 * 132];
    const int t = threadIdx.x;
    const int lane = t & 31, g = t >> 5;
    const int c4 = lane << 2;
    const long row0 = (long)blockIdx.x * 64 + g * 8;
    f4 sc = *(const f4*)&ss[c4];
    f4 sh = *(const f4*)&ss[HDIM + c4];
    f4 sum = {0, 0, 0, 0}, sq = {0, 0, 0, 0};
#pragma unroll
    for (int rr = 0; rr < 8; ++rr) {
        long row = row0 + rr;
        float sn = snorm[row];
        f4 q = *(const f4*)&P[row * HDIM + c4];
        q.x = relu_f(fmaf(q.x, sc.x, sh.x)) * sn;
        q.y = relu_f(fmaf(q.y, sc.y, sh.y)) * sn;
        q.z = relu_f(fmaf(q.z, sc.z, sh.z)) * sn;
        q.w = relu_f(fmaf(q.w, sc.w, sh.w)) * sn;
        *(f4*)&P[row * HDIM + c4] = q;
        sum.x += q.x; sum.y += q.y; sum.z += q.z; sum.w += q.w;
        sq.x += q.x * q.x; sq.y += q.y * q.y; sq.z += q.z * q.z; sq.w += q.w * q.w;
    }
    *(f4*)&red[g * 132 + c4] = sum;
    __syncthreads();
    if (t < HDIM) {
        float s = 0;
#pragma unroll
        for (int gg = 0; gg < 8; ++gg) s += red[gg * 132 + t];
        atomicAdd(&stats[t], s);
    }
    __syncthreads();
    *(f4*)&red[g * 132 + c4] = sq;
    __syncthreads();
    if (t < HDIM) {
        float s = 0;
#pragma unroll
        for (int gg = 0; gg < 8; ++gg) s += red[gg * 132 + t];
        atomicAdd(&stats[HDIM + t], s);
    }
}

// scale/shift from stats
__global__ void bn_finalize(const float* __restrict__ stats, const float* __restrict__ gamma,
                            const float* __restrict__ beta, float* __restrict__ ss)
{
    int t = threadIdx.x;
    const float inv_n = 1.0f / (float)NNODES;
    float mean = stats[t] * inv_n;
    float var = stats[HDIM + t] * inv_n - mean * mean;
    float scale = gamma[t] * rsqrtf(var + 1e-5f);
    ss[t] = scale;
    ss[HDIM + t] = beta[t] - mean * scale;
}

// H = relu(P*sc+sh) + HIN
__global__ void fin_res(const float* __restrict__ P, const float* __restrict__ ss,
                        const float* __restrict__ HIN, float* __restrict__ H)
{
    size_t idx = (size_t)blockIdx.x * 256 + threadIdx.x;  // float4 index
    int c4 = (idx & 31) << 2;
    f4 sc = *(const f4*)&ss[c4];
    f4 sh = *(const f4*)&ss[HDIM + c4];
    f4 q = ((const f4*)P)[idx];
    f4 hin = ((const f4*)HIN)[idx];
    q.x = relu_f(fmaf(q.x, sc.x, sh.x)) + hin.x;
    q.y = relu_f(fmaf(q.y, sc.y, sh.y)) + hin.y;
    q.z = relu_f(fmaf(q.z, sc.z, sh.z)) + hin.z;
    q.w = relu_f(fmaf(q.w, sc.w, sh.w)) + hin.w;
    ((f4*)H)[idx] = q;
}

// last layer: d[n] = (relu(P*sc+sh)+HIN) . v ; gsum[gid[n]] += d[n]
__global__ void fin_last(const float* __restrict__ P, const float* __restrict__ ss,
                         const float* __restrict__ HIN, const float* __restrict__ v,
                         const int* __restrict__ gid, float* __restrict__ gsum)
{
    int t = threadIdx.x;
    int lane = t & 31;
    long n = (long)blockIdx.x * 8 + (t >> 5);
    int c4 = lane << 2;
    f4 sc = *(const f4*)&ss[c4];
    f4 sh = *(const f4*)&ss[HDIM + c4];
    f4 q = *(const f4*)&P[n * HDIM + c4];
    f4 hin = *(const f4*)&HIN[n * HDIM + c4];
    f4 vv = *(const f4*)&v[c4];
    float d = 0;
    d += (relu_f(fmaf(q.x, sc.x, sh.x)) + hin.x) * vv.x;
    d += (relu_f(fmaf(q.y, sc.y, sh.y)) + hin.y) * vv.y;
    d += (relu_f(fmaf(q.z, sc.z, sh.z)) + hin.z) * vv.z;
    d += (relu_f(fmaf(q.w, sc.w, sh.w)) + hin.w) * vv.w;
#pragma unroll
    for (int off = 16; off > 0; off >>= 1) d += __shfl_down(d, off, 32);
    if (lane == 0) atomicAdd(&gsum[gid[n]], d);
}

__global__ void gcnt_kernel(const int* __restrict__ gid, float* __restrict__ gcnt)
{
    int n = blockIdx.x * 256 + threadIdx.x;
    if (n < NNODES) atomicAdd(&gcnt[gid[n]], 1.0f);
}

__global__ void v_kernel(const float* __restrict__ W_ro, const float* __restrict__ W_pred,
                         float* __restrict__ v)
{
    int t = threadIdx.x;
    if (t < HDIM) {
        float s = 0;
        for (int j = 0; j < HDIM; ++j) s += W_ro[t * HDIM + j] * W_pred[j];
        v[t] = s;
    }
}

__global__ void score_kernel(const float* __restrict__ gsum, const float* __restrict__ gcnt,
                             const float* __restrict__ b_pred, float* __restrict__ out)
{
    int g = blockIdx.x * 256 + threadIdx.x;
    if (g < NGRAPH) out[g] = gsum[g] / fmaxf(gcnt[g], 1.0f) + b_pred[0];
}

extern "C" void kernel_launch(void* const* d_in, const int* in_sizes, int n_in,
                              void* d_out, int out_size, void* d_ws, size_t ws_size,
                              hipStream_t stream)
{
    const float* h_raw   = (const float*)d_in[0];
    const int*   src     = (const int*)d_in[1];
    const int*   dst     = (const int*)d_in[2];
    const int*   gid     = (const int*)d_in[3];
    const float* snorm   = (const float*)d_in[4];
    const float* W_emb   = (const float*)d_in[5];
    const float* eps_gin = (const float*)d_in[6];
    const float* W1      = (const float*)d_in[7];
    const float* b1      = (const float*)d_in[8];
    const float* bn1_g   = (const float*)d_in[9];
    const float* bn1_b   = (const float*)d_in[10];
    const float* W2      = (const float*)d_in[11];
    const float* b2      = (const float*)d_in[12];
    const float* bn2_g   = (const float*)d_in[13];
    const float* bn2_b   = (const float*)d_in[14];
    const float* bn3_g   = (const float*)d_in[15];
    const float* bn3_b   = (const float*)d_in[16];
    const float* W_ro    = (const float*)d_in[17];
    const float* W_pred  = (const float*)d_in[18];
    const float* b_pred  = (const float*)d_in[19];
    float* out = (float*)d_out;

    float* ws = (float*)d_ws;
    const size_t NH = (size_t)NNODES * HDIM;
    float* HIN  = ws;
    float* Hbuf = ws + NH;
    float* P    = ws + 2 * NH;
    float* Z    = ws + 3 * NH;
    float* statsb = Z;                 // 12 * 256
    float* gsum   = Z + 12 * 256;      // 8000
    float* gcnt   = gsum + NGRAPH;     // 8000
    float* ssb    = Z + 19072;         // 12 * 256
    float* vvec   = ssb + 12 * 256;    // 128

    hipMemsetAsync(Z, 0, 19072 * sizeof(float), stream);
    gcnt_kernel<<<(NNODES + 255) / 256, 256, 0, stream>>>(gid, gcnt);
    v_kernel<<<1, 128, 0, stream>>>(W_ro, W_pred, vvec);

    // embedding: HIN = h_raw @ W_emb
    gemm_fused<ADIM, 101, false, false>
        <<<NNODES / 64, 256, 0, stream>>>(h_raw, W_emb, nullptr, nullptr, HIN, nullptr);

    const float* hcur = HIN;
    for (int i = 0; i < NLAYER; ++i) {
        float* st1 = statsb + (i * 3 + 0) * 256; float* ss1 = ssb + (i * 3 + 0) * 256;
        float* st2 = statsb + (i * 3 + 1) * 256; float* ss2 = ssb + (i * 3 + 1) * 256;
        float* st3 = statsb + (i * 3 + 2) * 256; float* ss3 = ssb + (i * 3 + 2) * 256;

        build_x<<<NH / 4 / 256, 256, 0, stream>>>(hcur, eps_gin, i, P);
        scatter_add<<<(size_t)NEDGES * 32 / 256, 256, 0, stream>>>(hcur, src, dst, P);
        gemm_fused<HDIM, 133, false, true>
            <<<NNODES / 64, 256, 0, stream>>>(P, W1 + i * HDIM * HDIM, b1 + i * HDIM,
                                              nullptr, P, st1);
        bn_finalize<<<1, 128, 0, stream>>>(st1, bn1_g + i * HDIM, bn1_b + i * HDIM, ss1);
        gemm_fused<HDIM, 133, true, true>
            <<<NNODES / 64, 256, 0, stream>>>(P, W2 + i * HDIM * HDIM, b2 + i * HDIM,
                                              ss1, P, st2);
        bn_finalize<<<1, 128, 0, stream>>>(st2, bn2_g + i * HDIM, bn2_b + i * HDIM, ss2);
        x3_kernel<<<NNODES / 64, 256, 0, stream>>>(P, ss2, snorm, st3);
        bn_finalize<<<1, 128, 0, stream>>>(st3, bn3_g + i * HDIM, bn3_b + i * HDIM, ss3);

        if (i < NLAYER - 1) {
            fin_res<<<NH / 4 / 256, 256, 0, stream>>>(P, ss3, HIN, Hbuf);
            hcur = Hbuf;
        } else {
            fin_last<<<NNODES / 8, 256, 0, stream>>>(P, ss3, HIN, vvec, gid, gsum);
        }
    }
    score_kernel<<<(NGRAPH + 255) / 256, 256, 0, stream>>>(gsum, gcnt, b_pred, out);
}

// Round 3
// 2526.909 us; speedup vs baseline: 2.0086x; 2.0086x over previous
//
#include <hip/hip_runtime.h>

#define NNODES 200000
#define NEDGES 400000
#define NGRAPH 8000
#define ADIM 100
#define HDIM 128
#define NLAYER 4
#define SCANB 2048   // elements per scan block (256 thr * 8)
#define NSCANB ((NNODES + SCANB - 1) / SCANB)   // 98

typedef float4 f4;

__device__ __forceinline__ float relu_f(float x) { return fmaxf(x, 0.0f); }

// ---------------------------------------------------------------------------
// GEMM: C[N,128] = f(A)[N,K] @ W[K,128] (+bias); optional column stats of C.
// One block = 64 rows x full 128 cols  ->  in-place (C==A) is safe.
// ---------------------------------------------------------------------------
template <int K, int PA, bool SSRELU, bool STATS>
__global__ __launch_bounds__(256, 1) void gemm_fused(
    const float* __restrict__ A, const float* __restrict__ W,
    const float* __restrict__ bias, const float* __restrict__ ssin,
    float* __restrict__ C, float* __restrict__ stats)
{
    __shared__ float Wl[K * HDIM];
    __shared__ float Al[64 * PA];
    __shared__ float red[STATS ? 16 * 130 : 1];

    const int t = threadIdx.x;
    const long row0 = (long)blockIdx.x * 64;

    for (int idx = t; idx < K * (HDIM / 4); idx += 256) {
        int k = idx >> 5;
        int c4 = (idx & 31) << 2;
        *(f4*)&Wl[k * HDIM + c4] = *(const f4*)&W[k * HDIM + c4];
    }
    for (int idx = t; idx < 64 * (K / 4); idx += 256) {
        int r = idx / (K / 4);
        int c4 = (idx % (K / 4)) << 2;
        f4 a = *(const f4*)&A[(row0 + r) * K + c4];
        if (SSRELU) {
            f4 sc = *(const f4*)&ssin[c4];
            f4 sh = *(const f4*)&ssin[K + c4];
            a.x = relu_f(fmaf(a.x, sc.x, sh.x));
            a.y = relu_f(fmaf(a.y, sc.y, sh.y));
            a.z = relu_f(fmaf(a.z, sc.z, sh.z));
            a.w = relu_f(fmaf(a.w, sc.w, sh.w));
        }
        float* p = &Al[r * PA + c4];
        p[0] = a.x; p[1] = a.y; p[2] = a.z; p[3] = a.w;
    }
    __syncthreads();

    const int tr = t & 15;
    const int tc = t >> 4;

    float acc[4][8];
#pragma unroll
    for (int i = 0; i < 4; ++i)
#pragma unroll
        for (int j = 0; j < 8; ++j) acc[i][j] = 0.0f;

#pragma unroll 4
    for (int k = 0; k < K; ++k) {
        float av[4];
#pragma unroll
        for (int i = 0; i < 4; ++i) av[i] = Al[(4 * tr + i) * PA + k];
        float bv[8];
        *(f4*)&bv[0] = *(const f4*)&Wl[k * HDIM + 8 * tc];
        *(f4*)&bv[4] = *(const f4*)&Wl[k * HDIM + 8 * tc + 4];
#pragma unroll
        for (int i = 0; i < 4; ++i)
#pragma unroll
            for (int j = 0; j < 8; ++j) acc[i][j] = fmaf(av[i], bv[j], acc[i][j]);
    }

    float bv[8] = {0, 0, 0, 0, 0, 0, 0, 0};
    if (STATS) {
        *(f4*)&bv[0] = *(const f4*)&bias[8 * tc];
        *(f4*)&bv[4] = *(const f4*)&bias[8 * tc + 4];
    }
    float psum[8] = {0, 0, 0, 0, 0, 0, 0, 0};
    float psq[8] = {0, 0, 0, 0, 0, 0, 0, 0};
#pragma unroll
    for (int i = 0; i < 4; ++i) {
        float outv[8];
#pragma unroll
        for (int j = 0; j < 8; ++j) {
            float val = acc[i][j] + bv[j];
            outv[j] = val;
            if (STATS) { psum[j] += val; psq[j] += val * val; }
        }
        long row = row0 + 4 * tr + i;
        *(f4*)&C[row * HDIM + 8 * tc] = *(f4*)&outv[0];
        *(f4*)&C[row * HDIM + 8 * tc + 4] = *(f4*)&outv[4];
    }

    if (STATS) {
#pragma unroll
        for (int j = 0; j < 8; ++j) red[tr * 130 + 8 * tc + j] = psum[j];
        __syncthreads();
        if (t < HDIM) {
            float s = 0;
#pragma unroll
            for (int r = 0; r < 16; ++r) s += red[r * 130 + t];
            atomicAdd(&stats[t], s);
        }
        __syncthreads();
#pragma unroll
        for (int j = 0; j < 8; ++j) red[tr * 130 + 8 * tc + j] = psq[j];
        __syncthreads();
        if (t < HDIM) {
            float s = 0;
#pragma unroll
            for (int r = 0; r < 16; ++r) s += red[r * 130 + t];
            atomicAdd(&stats[HDIM + t], s);
        }
    }
}

// ---------------- CSR build (per launch; graph is static per call) ----------
__global__ void deg_kernel(const int* __restrict__ dst, int* __restrict__ deg)
{
    int e = blockIdx.x * 256 + threadIdx.x;
    if (e < NEDGES) atomicAdd(&deg[dst[e]], 1);
}

// per-block exclusive scan of deg (blocks of 2048), write within-block
// exclusive prefix into rowptr, block total into bsum
__global__ __launch_bounds__(256) void scan1(const int* __restrict__ deg,
                                             int* __restrict__ rowptr,
                                             int* __restrict__ bsum)
{
    __shared__ int lds[256];
    const int t = threadIdx.x;
    const long base = (long)blockIdx.x * SCANB + t * 8;
    int v[8];
    int s = 0;
#pragma unroll
    for (int j = 0; j < 8; ++j) {
        long idx = base + j;
        v[j] = (idx < NNODES) ? deg[idx] : 0;
        s += v[j];
    }
    lds[t] = s;
    __syncthreads();
    // Hillis-Steele inclusive scan
    for (int d = 1; d < 256; d <<= 1) {
        int x = (t >= d) ? lds[t - d] : 0;
        __syncthreads();
        lds[t] += x;
        __syncthreads();
    }
    int off = lds[t] - s;  // exclusive
    if (t == 255) bsum[blockIdx.x] = lds[255];
#pragma unroll
    for (int j = 0; j < 8; ++j) {
        long idx = base + j;
        if (idx < NNODES) rowptr[idx] = off;
        off += v[j];
    }
}

// exclusive scan of the (<=128) block sums, in place
__global__ void scan2(int* __restrict__ bsum)
{
    __shared__ int lds[128];
    const int t = threadIdx.x;
    int v = (t < NSCANB) ? bsum[t] : 0;
    lds[t] = v;
    __syncthreads();
    for (int d = 1; d < 128; d <<= 1) {
        int x = (t >= d) ? lds[t - d] : 0;
        __syncthreads();
        lds[t] += x;
        __syncthreads();
    }
    if (t < NSCANB) bsum[t] = lds[t] - v;  // exclusive
}

// add block offsets; init cursor; set rowptr[N]
__global__ void scan3(int* __restrict__ rowptr, const int* __restrict__ bsum,
                      int* __restrict__ cursor)
{
    long i = (long)blockIdx.x * 256 + threadIdx.x;
    if (i < NNODES) {
        int r = rowptr[i] + bsum[i / SCANB];
        rowptr[i] = r;
        cursor[i] = r;
    }
    if (i == 0) rowptr[NNODES] = NEDGES;
}

__global__ void fill_eidx(const int* __restrict__ src, const int* __restrict__ dst,
                          int* __restrict__ cursor, int* __restrict__ eidx)
{
    int e = blockIdx.x * 256 + threadIdx.x;
    if (e < NEDGES) {
        int pos = atomicAdd(&cursor[dst[e]], 1);
        eidx[pos] = src[e];
    }
}

// ---------------- aggregation: P[n] = (1+eps)*H[n] + sum_in H[src] ----------
__global__ __launch_bounds__(256) void agg_kernel(
    const float* __restrict__ H, const int* __restrict__ rowptr,
    const int* __restrict__ eidx, const float* __restrict__ eps_gin, int layer,
    float* __restrict__ P)
{
    const int t = threadIdx.x;
    const int lane = t & 31;
    const long n = (long)blockIdx.x * 8 + (t >> 5);
    const int c4 = lane << 2;
    const float s = 1.0f + eps_gin[layer];
    f4 acc = *(const f4*)&H[n * HDIM + c4];
    acc.x *= s; acc.y *= s; acc.z *= s; acc.w *= s;
    const int b = rowptr[n], e = rowptr[n + 1];
    for (int i = b; i < e; ++i) {
        int m = eidx[i];
        f4 v = *(const f4*)&H[(size_t)m * HDIM + c4];
        acc.x += v.x; acc.y += v.y; acc.z += v.z; acc.w += v.w;
    }
    *(f4*)&P[n * HDIM + c4] = acc;
}

// P = relu(P*sc+sh) * snorm (in place), stats of result
__global__ __launch_bounds__(256) void x3_kernel(float* __restrict__ P,
                                                 const float* __restrict__ ss,
                                                 const float* __restrict__ snorm,
                                                 float* __restrict__ stats)
{
    __shared__ float red[8 * 132];
    const int t = threadIdx.x;
    const int lane = t & 31, g = t >> 5;
    const int c4 = lane << 2;
    const long row0 = (long)blockIdx.x * 64 + g * 8;
    f4 sc = *(const f4*)&ss[c4];
    f4 sh = *(const f4*)&ss[HDIM + c4];
    f4 sum = {0, 0, 0, 0}, sq = {0, 0, 0, 0};
#pragma unroll
    for (int rr = 0; rr < 8; ++rr) {
        long row = row0 + rr;
        float sn = snorm[row];
        f4 q = *(const f4*)&P[row * HDIM + c4];
        q.x = relu_f(fmaf(q.x, sc.x, sh.x)) * sn;
        q.y = relu_f(fmaf(q.y, sc.y, sh.y)) * sn;
        q.z = relu_f(fmaf(q.z, sc.z, sh.z)) * sn;
        q.w = relu_f(fmaf(q.w, sc.w, sh.w)) * sn;
        *(f4*)&P[row * HDIM + c4] = q;
        sum.x += q.x; sum.y += q.y; sum.z += q.z; sum.w += q.w;
        sq.x += q.x * q.x; sq.y += q.y * q.y; sq.z += q.z * q.z; sq.w += q.w * q.w;
    }
    *(f4*)&red[g * 132 + c4] = sum;
    __syncthreads();
    if (t < HDIM) {
        float s = 0;
#pragma unroll
        for (int gg = 0; gg < 8; ++gg) s += red[gg * 132 + t];
        atomicAdd(&stats[t], s);
    }
    __syncthreads();
    *(f4*)&red[g * 132 + c4] = sq;
    __syncthreads();
    if (t < HDIM) {
        float s = 0;
#pragma unroll
        for (int gg = 0; gg < 8; ++gg) s += red[gg * 132 + t];
        atomicAdd(&stats[HDIM + t], s);
    }
}

__global__ void bn_finalize(const float* __restrict__ stats, const float* __restrict__ gamma,
                            const float* __restrict__ beta, float* __restrict__ ss)
{
    int t = threadIdx.x;
    const float inv_n = 1.0f / (float)NNODES;
    float mean = stats[t] * inv_n;
    float var = stats[HDIM + t] * inv_n - mean * mean;
    float scale = gamma[t] * rsqrtf(var + 1e-5f);
    ss[t] = scale;
    ss[HDIM + t] = beta[t] - mean * scale;
}

// H = relu(P*sc+sh) + HIN
__global__ void fin_res(const float* __restrict__ P, const float* __restrict__ ss,
                        const float* __restrict__ HIN, float* __restrict__ H)
{
    size_t idx = (size_t)blockIdx.x * 256 + threadIdx.x;
    int c4 = (idx & 31) << 2;
    f4 sc = *(const f4*)&ss[c4];
    f4 sh = *(const f4*)&ss[HDIM + c4];
    f4 q = ((const f4*)P)[idx];
    f4 hin = ((const f4*)HIN)[idx];
    q.x = relu_f(fmaf(q.x, sc.x, sh.x)) + hin.x;
    q.y = relu_f(fmaf(q.y, sc.y, sh.y)) + hin.y;
    q.z = relu_f(fmaf(q.z, sc.z, sh.z)) + hin.z;
    q.w = relu_f(fmaf(q.w, sc.w, sh.w)) + hin.w;
    ((f4*)H)[idx] = q;
}

// last layer: d[n] = (relu(P*sc+sh)+HIN) . v ; gsum[gid[n]] += d[n]
__global__ void fin_last(const float* __restrict__ P, const float* __restrict__ ss,
                         const float* __restrict__ HIN, const float* __restrict__ v,
                         const int* __restrict__ gid, float* __restrict__ gsum)
{
    int t = threadIdx.x;
    int lane = t & 31;
    long n = (long)blockIdx.x * 8 + (t >> 5);
    int c4 = lane << 2;
    f4 sc = *(const f4*)&ss[c4];
    f4 sh = *(const f4*)&ss[HDIM + c4];
    f4 q = *(const f4*)&P[n * HDIM + c4];
    f4 hin = *(const f4*)&HIN[n * HDIM + c4];
    f4 vv = *(const f4*)&v[c4];
    float d = 0;
    d += (relu_f(fmaf(q.x, sc.x, sh.x)) + hin.x) * vv.x;
    d += (relu_f(fmaf(q.y, sc.y, sh.y)) + hin.y) * vv.y;
    d += (relu_f(fmaf(q.z, sc.z, sh.z)) + hin.z) * vv.z;
    d += (relu_f(fmaf(q.w, sc.w, sh.w)) + hin.w) * vv.w;
#pragma unroll
    for (int off = 16; off > 0; off >>= 1) d += __shfl_down(d, off, 32);
    if (lane == 0) atomicAdd(&gsum[gid[n]], d);
}

__global__ void gcnt_kernel(const int* __restrict__ gid, float* __restrict__ gcnt)
{
    int n = blockIdx.x * 256 + threadIdx.x;
    if (n < NNODES) atomicAdd(&gcnt[gid[n]], 1.0f);
}

__global__ void v_kernel(const float* __restrict__ W_ro, const float* __restrict__ W_pred,
                         float* __restrict__ v)
{
    int t = threadIdx.x;
    if (t < HDIM) {
        float s = 0;
        for (int j = 0; j < HDIM; ++j) s += W_ro[t * HDIM + j] * W_pred[j];
        v[t] = s;
    }
}

__global__ void score_kernel(const float* __restrict__ gsum, const float* __restrict__ gcnt,
                             const float* __restrict__ b_pred, float* __restrict__ out)
{
    int g = blockIdx.x * 256 + threadIdx.x;
    if (g < NGRAPH) out[g] = gsum[g] / fmaxf(gcnt[g], 1.0f) + b_pred[0];
}

extern "C" void kernel_launch(void* const* d_in, const int* in_sizes, int n_in,
                              void* d_out, int out_size, void* d_ws, size_t ws_size,
                              hipStream_t stream)
{
    const float* h_raw   = (const float*)d_in[0];
    const int*   src     = (const int*)d_in[1];
    const int*   dst     = (const int*)d_in[2];
    const int*   gid     = (const int*)d_in[3];
    const float* snorm   = (const float*)d_in[4];
    const float* W_emb   = (const float*)d_in[5];
    const float* eps_gin = (const float*)d_in[6];
    const float* W1      = (const float*)d_in[7];
    const float* b1      = (const float*)d_in[8];
    const float* bn1_g   = (const float*)d_in[9];
    const float* bn1_b   = (const float*)d_in[10];
    const float* W2      = (const float*)d_in[11];
    const float* b2      = (const float*)d_in[12];
    const float* bn2_g   = (const float*)d_in[13];
    const float* bn2_b   = (const float*)d_in[14];
    const float* bn3_g   = (const float*)d_in[15];
    const float* bn3_b   = (const float*)d_in[16];
    const float* W_ro    = (const float*)d_in[17];
    const float* W_pred  = (const float*)d_in[18];
    const float* b_pred  = (const float*)d_in[19];
    float* out = (float*)d_out;

    float* ws = (float*)d_ws;
    const size_t NH = (size_t)NNODES * HDIM;
    float* HIN  = ws;
    float* Hbuf = ws + NH;
    float* P    = ws + 2 * NH;
    float* Z    = ws + 3 * NH;
    float* statsb = Z;                 // 12 * 256
    float* gsum   = Z + 12 * 256;      // 8000
    float* gcnt   = gsum + NGRAPH;     // 8000
    float* ssb    = Z + 19072;         // 12 * 256
    float* vvec   = ssb + 12 * 256;    // 128

    int* ibase  = (int*)(ws + 3 * NH + 32768);
    int* rowptr = ibase;                       // N+1
    int* deg    = rowptr + NNODES + 1;         // N
    int* cursor = deg + NNODES;                // N
    int* bsum   = cursor + NNODES;             // 128
    int* eidx   = bsum + 128;                  // E

    hipMemsetAsync(Z, 0, 19072 * sizeof(float), stream);
    hipMemsetAsync(deg, 0, NNODES * sizeof(int), stream);

    gcnt_kernel<<<(NNODES + 255) / 256, 256, 0, stream>>>(gid, gcnt);
    v_kernel<<<1, 128, 0, stream>>>(W_ro, W_pred, vvec);

    // CSR build
    deg_kernel<<<(NEDGES + 255) / 256, 256, 0, stream>>>(dst, deg);
    scan1<<<NSCANB, 256, 0, stream>>>(deg, rowptr, bsum);
    scan2<<<1, 128, 0, stream>>>(bsum);
    scan3<<<(NNODES + 255) / 256, 256, 0, stream>>>(rowptr, bsum, cursor);
    fill_eidx<<<(NEDGES + 255) / 256, 256, 0, stream>>>(src, dst, cursor, eidx);

    // embedding: HIN = h_raw @ W_emb
    gemm_fused<ADIM, 101, false, false>
        <<<NNODES / 64, 256, 0, stream>>>(h_raw, W_emb, nullptr, nullptr, HIN, nullptr);

    const float* hcur = HIN;
    for (int i = 0; i < NLAYER; ++i) {
        float* st1 = statsb + (i * 3 + 0) * 256; float* ss1 = ssb + (i * 3 + 0) * 256;
        float* st2 = statsb + (i * 3 + 1) * 256; float* ss2 = ssb + (i * 3 + 1) * 256;
        float* st3 = statsb + (i * 3 + 2) * 256; float* ss3 = ssb + (i * 3 + 2) * 256;

        agg_kernel<<<NNODES / 8, 256, 0, stream>>>(hcur, rowptr, eidx, eps_gin, i, P);
        gemm_fused<HDIM, 133, false, true>
            <<<NNODES / 64, 256, 0, stream>>>(P, W1 + i * HDIM * HDIM, b1 + i * HDIM,
                                              nullptr, P, st1);
        bn_finalize<<<1, 128, 0, stream>>>(st1, bn1_g + i * HDIM, bn1_b + i * HDIM, ss1);
        gemm_fused<HDIM, 133, true, true>
            <<<NNODES / 64, 256, 0, stream>>>(P, W2 + i * HDIM * HDIM, b2 + i * HDIM,
                                              ss1, P, st2);
        bn_finalize<<<1, 128, 0, stream>>>(st2, bn2_g + i * HDIM, bn2_b + i * HDIM, ss2);
        x3_kernel<<<NNODES / 64, 256, 0, stream>>>(P, ss2, snorm, st3);
        bn_finalize<<<1, 128, 0, stream>>>(st3, bn3_g + i * HDIM, bn3_b + i * HDIM, ss3);

        if (i < NLAYER - 1) {
            fin_res<<<NH / 4 / 256, 256, 0, stream>>>(P, ss3, HIN, Hbuf);
            hcur = Hbuf;
        } else {
            fin_last<<<NNODES / 8, 256, 0, stream>>>(P, ss3, HIN, vvec, gid, gsum);
        }
    }
    score_kernel<<<(NGRAPH + 255) / 256, 256, 0, stream>>>(gsum, gcnt, b_pred, out);
}

// Round 4
// 1786.904 us; speedup vs baseline: 2.8404x; 1.4141x over previous
//
#include <hip/hip_runtime.h>

#define NNODES 200000
#define NEDGES 400000
#define NGRAPH 8000
#define ADIM 100
#define HDIM 128
#define NLAYER 4
#define SCANB 2048
#define NSCANB ((NNODES + SCANB - 1) / SCANB)   // 98

typedef float4 f4;
typedef __attribute__((ext_vector_type(8))) short bf16x8;
typedef __attribute__((ext_vector_type(4))) float f32x4;

__device__ __forceinline__ float relu_f(float x) { return fmaxf(x, 0.0f); }

// f32 -> bf16 (RNE)
__device__ __forceinline__ unsigned short f2b(float x)
{
    unsigned int u = __float_as_uint(x);
    u = (u + 0x7FFFu + ((u >> 16) & 1u)) >> 16;
    return (unsigned short)u;
}

// ---------------------------------------------------------------------------
// Weight pre-transpose+convert: Wtb[m][n][k] = bf16(W_m[k][n]), m=0 emb (k<100,
// zero-padded to 128), m=1..4 W1[i], m=5..8 W2[i].
// ---------------------------------------------------------------------------
__global__ void wconv(const float* __restrict__ W_emb, const float* __restrict__ W1,
                      const float* __restrict__ W2, unsigned short* __restrict__ Wtb)
{
    int id = blockIdx.x * 256 + threadIdx.x;   // 9*16384 total
    int m = id >> 14;
    int r = id & 16383;
    int n = r >> 7;
    int k = r & 127;
    float v;
    if (m == 0)      v = (k < ADIM) ? W_emb[k * HDIM + n] : 0.0f;
    else if (m <= 4) v = W1[(size_t)(m - 1) * HDIM * HDIM + k * HDIM + n];
    else             v = W2[(size_t)(m - 5) * HDIM * HDIM + k * HDIM + n];
    Wtb[id] = f2b(v);
}

// ---------------------------------------------------------------------------
// MFMA GEMM: C[N,128] = f(A)[N,KSRC(->128)] @ W[128,128] (+bias), col stats.
// Block = 64 rows x 128 cols, 4 waves (16 rows each). In-place safe (C==A).
// A staged f32->bf16 in LDS; Wt ([n][k] bf16) staged in LDS. Pad 136 shorts.
// ---------------------------------------------------------------------------
template <int KSRC, bool SSRELU, bool STATS>
__global__ __launch_bounds__(256, 2) void gemm_mfma(
    const float* __restrict__ A, const unsigned short* __restrict__ Wt,
    const float* __restrict__ bias, const float* __restrict__ ssin,
    float* __restrict__ C, float* __restrict__ stats)
{
    __shared__ unsigned short Asub[64 * 136];
    __shared__ unsigned short Wl[128 * 136];

    const int t = threadIdx.x;
    const long row0 = (long)blockIdx.x * 64;

    // stage Wt [128][128] bf16 -> LDS
    for (int idx = t; idx < 128 * 16; idx += 256) {
        int n = idx >> 4, c8 = (idx & 15) << 3;
        *(ulonglong2*)&Wl[n * 136 + c8] = *(const ulonglong2*)&Wt[n * 128 + c8];
    }
    // stage A tile [64][128], f32 -> bf16 (optional BN-apply+ReLU first)
    for (int idx = t; idx < 64 * 32; idx += 256) {
        int r = idx >> 5, c4 = (idx & 31) << 2;
        f4 a;
        if (KSRC == 128 || c4 < KSRC) a = *(const f4*)&A[(row0 + r) * KSRC + c4];
        else                          a = make_float4(0.f, 0.f, 0.f, 0.f);
        if (SSRELU) {
            f4 sc = *(const f4*)&ssin[c4];
            f4 sh = *(const f4*)&ssin[HDIM + c4];
            a.x = relu_f(fmaf(a.x, sc.x, sh.x));
            a.y = relu_f(fmaf(a.y, sc.y, sh.y));
            a.z = relu_f(fmaf(a.z, sc.z, sh.z));
            a.w = relu_f(fmaf(a.w, sc.w, sh.w));
        }
        ushort4 b;
        b.x = f2b(a.x); b.y = f2b(a.y); b.z = f2b(a.z); b.w = f2b(a.w);
        *(ushort4*)&Asub[r * 136 + c4] = b;
    }
    __syncthreads();

    const int w  = t >> 6;        // wave id: rows [16w,16w+16)
    const int l  = t & 63;
    const int lr = l & 15;        // row (A) / col (B,D) within 16
    const int lk = l >> 4;        // k-group / D row-group

    f32x4 acc[8];
#pragma unroll
    for (int f = 0; f < 8; ++f) acc[f] = (f32x4){0.f, 0.f, 0.f, 0.f};

#pragma unroll
    for (int ks = 0; ks < 4; ++ks) {
        bf16x8 af = *(bf16x8*)&Asub[(16 * w + lr) * 136 + ks * 32 + lk * 8];
#pragma unroll
        for (int f = 0; f < 8; ++f) {
            bf16x8 bf = *(bf16x8*)&Wl[(16 * f + lr) * 136 + ks * 32 + lk * 8];
            acc[f] = __builtin_amdgcn_mfma_f32_16x16x32_bf16(af, bf, acc[f], 0, 0, 0);
        }
    }

    // epilogue: bias add + store (D: row = lk*4+r, col = 16f+lr)
    float outv[8][4];
#pragma unroll
    for (int f = 0; f < 8; ++f) {
        float bv = STATS ? bias[16 * f + lr] : 0.0f;
#pragma unroll
        for (int r = 0; r < 4; ++r) {
            float val = acc[f][r] + bv;
            outv[f][r] = val;
            C[(row0 + 16 * w + lk * 4 + r) * HDIM + 16 * f + lr] = val;
        }
    }

    if (STATS) {
        __syncthreads();                       // Asub reads done -> reuse as red
        float* red = (float*)Asub;             // [16][132]
        const int rid = w * 4 + lk;            // 0..15
#pragma unroll
        for (int f = 0; f < 8; ++f)
            red[rid * 132 + 16 * f + lr] =
                outv[f][0] + outv[f][1] + outv[f][2] + outv[f][3];
        __syncthreads();
        if (t < HDIM) {
            float s = 0;
#pragma unroll
            for (int g = 0; g < 16; ++g) s += red[g * 132 + t];
            atomicAdd(&stats[t], s);
        }
        __syncthreads();
#pragma unroll
        for (int f = 0; f < 8; ++f)
            red[rid * 132 + 16 * f + lr] =
                outv[f][0] * outv[f][0] + outv[f][1] * outv[f][1] +
                outv[f][2] * outv[f][2] + outv[f][3] * outv[f][3];
        __syncthreads();
        if (t < HDIM) {
            float s = 0;
#pragma unroll
            for (int g = 0; g < 16; ++g) s += red[g * 132 + t];
            atomicAdd(&stats[HDIM + t], s);
        }
    }
}

// ---------------- CSR build (graph static per call) -------------------------
__global__ void deg_kernel(const int* __restrict__ dst, int* __restrict__ deg)
{
    int e = blockIdx.x * 256 + threadIdx.x;
    if (e < NEDGES) atomicAdd(&deg[dst[e]], 1);
}

__global__ __launch_bounds__(256) void scan1(const int* __restrict__ deg,
                                             int* __restrict__ rowptr,
                                             int* __restrict__ bsum)
{
    __shared__ int lds[256];
    const int t = threadIdx.x;
    const long base = (long)blockIdx.x * SCANB + t * 8;
    int v[8];
    int s = 0;
#pragma unroll
    for (int j = 0; j < 8; ++j) {
        long idx = base + j;
        v[j] = (idx < NNODES) ? deg[idx] : 0;
        s += v[j];
    }
    lds[t] = s;
    __syncthreads();
    for (int d = 1; d < 256; d <<= 1) {
        int x = (t >= d) ? lds[t - d] : 0;
        __syncthreads();
        lds[t] += x;
        __syncthreads();
    }
    int off = lds[t] - s;
    if (t == 255) bsum[blockIdx.x] = lds[255];
#pragma unroll
    for (int j = 0; j < 8; ++j) {
        long idx = base + j;
        if (idx < NNODES) rowptr[idx] = off;
        off += v[j];
    }
}

__global__ void scan2(int* __restrict__ bsum)
{
    __shared__ int lds[128];
    const int t = threadIdx.x;
    int v = (t < NSCANB) ? bsum[t] : 0;
    lds[t] = v;
    __syncthreads();
    for (int d = 1; d < 128; d <<= 1) {
        int x = (t >= d) ? lds[t - d] : 0;
        __syncthreads();
        lds[t] += x;
        __syncthreads();
    }
    if (t < NSCANB) bsum[t] = lds[t] - v;
}

__global__ void scan3(int* __restrict__ rowptr, const int* __restrict__ bsum,
                      int* __restrict__ cursor)
{
    long i = (long)blockIdx.x * 256 + threadIdx.x;
    if (i < NNODES) {
        int r = rowptr[i] + bsum[i / SCANB];
        rowptr[i] = r;
        cursor[i] = r;
    }
    if (i == 0) rowptr[NNODES] = NEDGES;
}

__global__ void fill_eidx(const int* __restrict__ src, const int* __restrict__ dst,
                          int* __restrict__ cursor, int* __restrict__ eidx)
{
    int e = blockIdx.x * 256 + threadIdx.x;
    if (e < NEDGES) {
        int pos = atomicAdd(&cursor[dst[e]], 1);
        eidx[pos] = src[e];
    }
}

// ---------------- aggregation: P[n] = (1+eps)*H[n] + sum_in H[src] ----------
__global__ __launch_bounds__(256) void agg_kernel(
    const float* __restrict__ H, const int* __restrict__ rowptr,
    const int* __restrict__ eidx, const float* __restrict__ eps_gin, int layer,
    float* __restrict__ P)
{
    const int t = threadIdx.x;
    const int lane = t & 31;
    const long n = (long)blockIdx.x * 8 + (t >> 5);
    const int c4 = lane << 2;
    const float s = 1.0f + eps_gin[layer];
    f4 acc = *(const f4*)&H[n * HDIM + c4];
    acc.x *= s; acc.y *= s; acc.z *= s; acc.w *= s;
    const int b = rowptr[n], e = rowptr[n + 1];
    for (int i = b; i < e; ++i) {
        int m = eidx[i];
        f4 v = *(const f4*)&H[(size_t)m * HDIM + c4];
        acc.x += v.x; acc.y += v.y; acc.z += v.z; acc.w += v.w;
    }
    *(f4*)&P[n * HDIM + c4] = acc;
}

// P = relu(P*sc+sh) * snorm (in place), stats of result
__global__ __launch_bounds__(256) void x3_kernel(float* __restrict__ P,
                                                 const float* __restrict__ ss,
                                                 const float* __restrict__ snorm,
                                                 float* __restrict__ stats)
{
    __shared__ float red[8 * 132];
    const int t = threadIdx.x;
    const int lane = t & 31, g = t >> 5;
    const int c4 = lane << 2;
    const long row0 = (long)blockIdx.x * 64 + g * 8;
    f4 sc = *(const f4*)&ss[c4];
    f4 sh = *(const f4*)&ss[HDIM + c4];
    f4 sum = {0, 0, 0, 0}, sq = {0, 0, 0, 0};
#pragma unroll
    for (int rr = 0; rr < 8; ++rr) {
        long row = row0 + rr;
        float sn = snorm[row];
        f4 q = *(const f4*)&P[row * HDIM + c4];
        q.x = relu_f(fmaf(q.x, sc.x, sh.x)) * sn;
        q.y = relu_f(fmaf(q.y, sc.y, sh.y)) * sn;
        q.z = relu_f(fmaf(q.z, sc.z, sh.z)) * sn;
        q.w = relu_f(fmaf(q.w, sc.w, sh.w)) * sn;
        *(f4*)&P[row * HDIM + c4] = q;
        sum.x += q.x; sum.y += q.y; sum.z += q.z; sum.w += q.w;
        sq.x += q.x * q.x; sq.y += q.y * q.y; sq.z += q.z * q.z; sq.w += q.w * q.w;
    }
    *(f4*)&red[g * 132 + c4] = sum;
    __syncthreads();
    if (t < HDIM) {
        float s = 0;
#pragma unroll
        for (int gg = 0; gg < 8; ++gg) s += red[gg * 132 + t];
        atomicAdd(&stats[t], s);
    }
    __syncthreads();
    *(f4*)&red[g * 132 + c4] = sq;
    __syncthreads();
    if (t < HDIM) {
        float s = 0;
#pragma unroll
        for (int gg = 0; gg < 8; ++gg) s += red[gg * 132 + t];
        atomicAdd(&stats[HDIM + t], s);
    }
}

__global__ void bn_finalize(const float* __restrict__ stats, const float* __restrict__ gamma,
                            const float* __restrict__ beta, float* __restrict__ ss)
{
    int t = threadIdx.x;
    const float inv_n = 1.0f / (float)NNODES;
    float mean = stats[t] * inv_n;
    float var = stats[HDIM + t] * inv_n - mean * mean;
    float scale = gamma[t] * rsqrtf(var + 1e-5f);
    ss[t] = scale;
    ss[HDIM + t] = beta[t] - mean * scale;
}

// H = relu(P*sc+sh) + HIN
__global__ void fin_res(const float* __restrict__ P, const float* __restrict__ ss,
                        const float* __restrict__ HIN, float* __restrict__ H)
{
    size_t idx = (size_t)blockIdx.x * 256 + threadIdx.x;
    int c4 = (idx & 31) << 2;
    f4 sc = *(const f4*)&ss[c4];
    f4 sh = *(const f4*)&ss[HDIM + c4];
    f4 q = ((const f4*)P)[idx];
    f4 hin = ((const f4*)HIN)[idx];
    q.x = relu_f(fmaf(q.x, sc.x, sh.x)) + hin.x;
    q.y = relu_f(fmaf(q.y, sc.y, sh.y)) + hin.y;
    q.z = relu_f(fmaf(q.z, sc.z, sh.z)) + hin.z;
    q.w = relu_f(fmaf(q.w, sc.w, sh.w)) + hin.w;
    ((f4*)H)[idx] = q;
}

// last layer: d[n] = (relu(P*sc+sh)+HIN) . v ; gsum[gid[n]] += d[n]
__global__ void fin_last(const float* __restrict__ P, const float* __restrict__ ss,
                         const float* __restrict__ HIN, const float* __restrict__ v,
                         const int* __restrict__ gid, float* __restrict__ gsum)
{
    int t = threadIdx.x;
    int lane = t & 31;
    long n = (long)blockIdx.x * 8 + (t >> 5);
    int c4 = lane << 2;
    f4 sc = *(const f4*)&ss[c4];
    f4 sh = *(const f4*)&ss[HDIM + c4];
    f4 q = *(const f4*)&P[n * HDIM + c4];
    f4 hin = *(const f4*)&HIN[n * HDIM + c4];
    f4 vv = *(const f4*)&v[c4];
    float d = 0;
    d += (relu_f(fmaf(q.x, sc.x, sh.x)) + hin.x) * vv.x;
    d += (relu_f(fmaf(q.y, sc.y, sh.y)) + hin.y) * vv.y;
    d += (relu_f(fmaf(q.z, sc.z, sh.z)) + hin.z) * vv.z;
    d += (relu_f(fmaf(q.w, sc.w, sh.w)) + hin.w) * vv.w;
#pragma unroll
    for (int off = 16; off > 0; off >>= 1) d += __shfl_down(d, off, 32);
    if (lane == 0) atomicAdd(&gsum[gid[n]], d);
}

__global__ void gcnt_kernel(const int* __restrict__ gid, float* __restrict__ gcnt)
{
    int n = blockIdx.x * 256 + threadIdx.x;
    if (n < NNODES) atomicAdd(&gcnt[gid[n]], 1.0f);
}

__global__ void v_kernel(const float* __restrict__ W_ro, const float* __restrict__ W_pred,
                         float* __restrict__ v)
{
    int t = threadIdx.x;
    if (t < HDIM) {
        float s = 0;
        for (int j = 0; j < HDIM; ++j) s += W_ro[t * HDIM + j] * W_pred[j];
        v[t] = s;
    }
}

__global__ void score_kernel(const float* __restrict__ gsum, const float* __restrict__ gcnt,
                             const float* __restrict__ b_pred, float* __restrict__ out)
{
    int g = blockIdx.x * 256 + threadIdx.x;
    if (g < NGRAPH) out[g] = gsum[g] / fmaxf(gcnt[g], 1.0f) + b_pred[0];
}

extern "C" void kernel_launch(void* const* d_in, const int* in_sizes, int n_in,
                              void* d_out, int out_size, void* d_ws, size_t ws_size,
                              hipStream_t stream)
{
    const float* h_raw   = (const float*)d_in[0];
    const int*   src     = (const int*)d_in[1];
    const int*   dst     = (const int*)d_in[2];
    const int*   gid     = (const int*)d_in[3];
    const float* snorm   = (const float*)d_in[4];
    const float* W_emb   = (const float*)d_in[5];
    const float* eps_gin = (const float*)d_in[6];
    const float* W1      = (const float*)d_in[7];
    const float* b1      = (const float*)d_in[8];
    const float* bn1_g   = (const float*)d_in[9];
    const float* bn1_b   = (const float*)d_in[10];
    const float* W2      = (const float*)d_in[11];
    const float* b2      = (const float*)d_in[12];
    const float* bn2_g   = (const float*)d_in[13];
    const float* bn2_b   = (const float*)d_in[14];
    const float* bn3_g   = (const float*)d_in[15];
    const float* bn3_b   = (const float*)d_in[16];
    const float* W_ro    = (const float*)d_in[17];
    const float* W_pred  = (const float*)d_in[18];
    const float* b_pred  = (const float*)d_in[19];
    float* out = (float*)d_out;

    float* ws = (float*)d_ws;
    const size_t NH = (size_t)NNODES * HDIM;
    float* HIN  = ws;
    float* Hbuf = ws + NH;
    float* P    = ws + 2 * NH;
    float* Z    = ws + 3 * NH;
    float* statsb = Z;                 // 12 * 256
    float* gsum   = Z + 12 * 256;      // 8000
    float* gcnt   = gsum + NGRAPH;     // 8000
    float* ssb    = Z + 19072;         // 12 * 256
    float* vvec   = ssb + 12 * 256;    // 128

    int* ibase  = (int*)(ws + 3 * NH + 32768);
    int* rowptr = ibase;                       // N+1
    int* deg    = rowptr + NNODES + 1;         // N (reused for Wtb after scan1)
    int* cursor = deg + NNODES;                // N
    int* bsum   = cursor + NNODES;             // 128
    int* eidx   = bsum + 128;                  // E
    // bf16 transposed weights live in the dead deg buffer (800KB >> 295KB)
    unsigned short* Wtb =
        (unsigned short*)(((uintptr_t)deg + 15) & ~(uintptr_t)15);

    hipMemsetAsync(Z, 0, 19072 * sizeof(float), stream);
    hipMemsetAsync(deg, 0, NNODES * sizeof(int), stream);

    gcnt_kernel<<<(NNODES + 255) / 256, 256, 0, stream>>>(gid, gcnt);
    v_kernel<<<1, 128, 0, stream>>>(W_ro, W_pred, vvec);

    // CSR build (deg consumed by scan1, then its space becomes Wtb)
    deg_kernel<<<(NEDGES + 255) / 256, 256, 0, stream>>>(dst, deg);
    scan1<<<NSCANB, 256, 0, stream>>>(deg, rowptr, bsum);
    scan2<<<1, 128, 0, stream>>>(bsum);
    scan3<<<(NNODES + 255) / 256, 256, 0, stream>>>(rowptr, bsum, cursor);
    fill_eidx<<<(NEDGES + 255) / 256, 256, 0, stream>>>(src, dst, cursor, eidx);

    // weights -> bf16 transposed [9][128][128]
    wconv<<<(9 * 16384) / 256, 256, 0, stream>>>(W_emb, W1, W2, Wtb);

    // embedding: HIN = h_raw @ W_emb  (K=100 zero-padded to 128)
    gemm_mfma<ADIM, false, false>
        <<<NNODES / 64, 256, 0, stream>>>(h_raw, Wtb, nullptr, nullptr, HIN, nullptr);

    const float* hcur = HIN;
    for (int i = 0; i < NLAYER; ++i) {
        float* st1 = statsb + (i * 3 + 0) * 256; float* ss1 = ssb + (i * 3 + 0) * 256;
        float* st2 = statsb + (i * 3 + 1) * 256; float* ss2 = ssb + (i * 3 + 1) * 256;
        float* st3 = statsb + (i * 3 + 2) * 256; float* ss3 = ssb + (i * 3 + 2) * 256;

        agg_kernel<<<NNODES / 8, 256, 0, stream>>>(hcur, rowptr, eidx, eps_gin, i, P);
        gemm_mfma<HDIM, false, true>
            <<<NNODES / 64, 256, 0, stream>>>(P, Wtb + (size_t)(1 + i) * 16384,
                                              b1 + i * HDIM, nullptr, P, st1);
        bn_finalize<<<1, 128, 0, stream>>>(st1, bn1_g + i * HDIM, bn1_b + i * HDIM, ss1);
        gemm_mfma<HDIM, true, true>
            <<<NNODES / 64, 256, 0, stream>>>(P, Wtb + (size_t)(5 + i) * 16384,
                                              b2 + i * HDIM, ss1, P, st2);
        bn_finalize<<<1, 128, 0, stream>>>(st2, bn2_g + i * HDIM, bn2_b + i * HDIM, ss2);
        x3_kernel<<<NNODES / 64, 256, 0, stream>>>(P, ss2, snorm, st3);
        bn_finalize<<<1, 128, 0, stream>>>(st3, bn3_g + i * HDIM, bn3_b + i * HDIM, ss3);

        if (i < NLAYER - 1) {
            fin_res<<<NH / 4 / 256, 256, 0, stream>>>(P, ss3, HIN, Hbuf);
            hcur = Hbuf;
        } else {
            fin_last<<<NNODES / 8, 256, 0, stream>>>(P, ss3, HIN, vvec, gid, gsum);
        }
    }
    score_kernel<<<(NGRAPH + 255) / 256, 256, 0, stream>>>(gsum, gcnt, b_pred, out);
}

// Round 5
// 1477.194 us; speedup vs baseline: 3.4359x; 1.2097x over previous
//
#include <hip/hip_runtime.h>

#define NNODES 200000
#define NEDGES 400000
#define NGRAPH 8000
#define ADIM 100
#define HDIM 128
#define NLAYER 4
#define SCANB 2048
#define NSCANB ((NNODES + SCANB - 1) / SCANB)   // 98
#define INV_N (1.0f / (float)NNODES)

typedef float4 f4;
typedef __attribute__((ext_vector_type(8))) short bf16x8;
typedef __attribute__((ext_vector_type(4))) float f32x4;

__device__ __forceinline__ float relu_f(float x) { return fmaxf(x, 0.0f); }

// f32 -> bf16 (RNE)
__device__ __forceinline__ unsigned short f2b(float x)
{
    unsigned int u = __float_as_uint(x);
    u = (u + 0x7FFFu + ((u >> 16) & 1u)) >> 16;
    return (unsigned short)u;
}
__device__ __forceinline__ float b2f(unsigned short b)
{
    return __uint_as_float(((unsigned int)b) << 16);
}

// ---------------------------------------------------------------------------
// Weight pre-transpose+convert: Wtb[m][n][k] = bf16(W_m[k][n])
// ---------------------------------------------------------------------------
__global__ void wconv(const float* __restrict__ W_emb, const float* __restrict__ W1,
                      const float* __restrict__ W2, unsigned short* __restrict__ Wtb)
{
    int id = blockIdx.x * 256 + threadIdx.x;   // 9*16384 total
    int m = id >> 14;
    int r = id & 16383;
    int n = r >> 7;
    int k = r & 127;
    float v;
    if (m == 0)      v = (k < ADIM) ? W_emb[k * HDIM + n] : 0.0f;
    else if (m <= 4) v = W1[(size_t)(m - 1) * HDIM * HDIM + k * HDIM + n];
    else             v = W2[(size_t)(m - 5) * HDIM * HDIM + k * HDIM + n];
    Wtb[id] = f2b(v);
}

// ---------------------------------------------------------------------------
// MFMA GEMM: C[N,128] = f(A) @ W (+bias), optional col stats.
// Block = 64 rows, 4 waves x 16 rows. A fragments loaded DIRECTLY from global
// (bf16 layout == fragment layout). W staged in LDS (pad 136). In-place safe.
// APPLY: A' = relu(A*sc + sh) with sc/sh finalized in-block from stIn.
// ---------------------------------------------------------------------------
template <bool EMB, bool APPLY, bool STATS>
__global__ __launch_bounds__(256, 3) void gemm_mfma(
    const void* __restrict__ Av, const unsigned short* __restrict__ Wt,
    const float* __restrict__ bias, const float* __restrict__ stIn,
    const float* __restrict__ gIn, const float* __restrict__ bIn,
    unsigned short* __restrict__ C, float* __restrict__ stOut)
{
    __shared__ unsigned short Wl[128 * 136];
    __shared__ float red[STATS ? 16 * 132 : 1];
    __shared__ float scb[APPLY ? 128 : 1];
    __shared__ float shb[APPLY ? 128 : 1];

    const int t = threadIdx.x;
    const long row0 = (long)blockIdx.x * 64;

    if (APPLY && t < 128) {
        float m = stIn[t] * INV_N;
        float v = stIn[128 + t] * INV_N - m * m;
        float s = gIn[t] * rsqrtf(v + 1e-5f);
        scb[t] = s; shb[t] = bIn[t] - m * s;
    }
    for (int idx = t; idx < 128 * 16; idx += 256) {
        int nr = idx >> 4, c8 = (idx & 15) << 3;
        *(bf16x8*)&Wl[nr * 136 + c8] = *(const bf16x8*)&Wt[nr * 128 + c8];
    }
    __syncthreads();

    const int w = t >> 6, l = t & 63;
    const int lr = l & 15, lk = l >> 4;
    const long arow = row0 + 16 * w + lr;

    bf16x8 af[4];
    if (EMB) {
        const float* A = (const float*)Av;
#pragma unroll
        for (int ks = 0; ks < 4; ++ks) {
            int k0 = ks * 32 + lk * 8;
            f4 a0 = {0, 0, 0, 0}, a1 = {0, 0, 0, 0};
            if (k0 < ADIM)      a0 = *(const f4*)&A[arow * ADIM + k0];
            if (k0 + 8 <= ADIM) a1 = *(const f4*)&A[arow * ADIM + k0 + 4];
            bf16x8 v;
            v[0] = (short)f2b(a0.x); v[1] = (short)f2b(a0.y);
            v[2] = (short)f2b(a0.z); v[3] = (short)f2b(a0.w);
            v[4] = (short)f2b(a1.x); v[5] = (short)f2b(a1.y);
            v[6] = (short)f2b(a1.z); v[7] = (short)f2b(a1.w);
            af[ks] = v;
        }
    } else {
        const unsigned short* A = (const unsigned short*)Av;
#pragma unroll
        for (int ks = 0; ks < 4; ++ks)
            af[ks] = *(const bf16x8*)&A[arow * HDIM + ks * 32 + lk * 8];
        if (APPLY) {
#pragma unroll
            for (int ks = 0; ks < 4; ++ks) {
                int k0 = ks * 32 + lk * 8;
                bf16x8 v = af[ks];
#pragma unroll
                for (int j = 0; j < 8; ++j) {
                    float x = b2f((unsigned short)v[j]);
                    x = relu_f(fmaf(x, scb[k0 + j], shb[k0 + j]));
                    v[j] = (short)f2b(x);
                }
                af[ks] = v;
            }
        }
    }

    f32x4 acc[8];
#pragma unroll
    for (int f = 0; f < 8; ++f) acc[f] = (f32x4){0.f, 0.f, 0.f, 0.f};
#pragma unroll
    for (int ks = 0; ks < 4; ++ks) {
#pragma unroll
        for (int f = 0; f < 8; ++f) {
            bf16x8 bfr = *(const bf16x8*)&Wl[(16 * f + lr) * 136 + ks * 32 + lk * 8];
            acc[f] = __builtin_amdgcn_mfma_f32_16x16x32_bf16(af[ks], bfr, acc[f], 0, 0, 0);
        }
    }

    float psum[8], psq[8];
#pragma unroll
    for (int f = 0; f < 8; ++f) {
        float bv = STATS ? bias[16 * f + lr] : 0.0f;
        float ps = 0, pq = 0;
#pragma unroll
        for (int r = 0; r < 4; ++r) {
            float val = acc[f][r] + bv;
            C[(row0 + 16 * w + lk * 4 + r) * HDIM + 16 * f + lr] = f2b(val);
            ps += val; pq += val * val;
        }
        psum[f] = ps; psq[f] = pq;
    }

    if (STATS) {
        const int rid = w * 4 + lk;
#pragma unroll
        for (int f = 0; f < 8; ++f) red[rid * 132 + 16 * f + lr] = psum[f];
        __syncthreads();
        if (t < 128) {
            float s = 0;
#pragma unroll
            for (int g = 0; g < 16; ++g) s += red[g * 132 + t];
            atomicAdd(&stOut[t], s);
        }
        __syncthreads();
#pragma unroll
        for (int f = 0; f < 8; ++f) red[rid * 132 + 16 * f + lr] = psq[f];
        __syncthreads();
        if (t < 128) {
            float s = 0;
#pragma unroll
            for (int g = 0; g < 16; ++g) s += red[g * 132 + t];
            atomicAdd(&stOut[128 + t], s);
        }
    }
}

// ---------------- CSR build (graph static per call) -------------------------
__global__ void deg_kernel(const int* __restrict__ dst, int* __restrict__ deg)
{
    int e = blockIdx.x * 256 + threadIdx.x;
    if (e < NEDGES) atomicAdd(&deg[dst[e]], 1);
}

__global__ __launch_bounds__(256) void scan1(const int* __restrict__ deg,
                                             int* __restrict__ rowptr,
                                             int* __restrict__ bsum)
{
    __shared__ int lds[256];
    const int t = threadIdx.x;
    const long base = (long)blockIdx.x * SCANB + t * 8;
    int v[8];
    int s = 0;
#pragma unroll
    for (int j = 0; j < 8; ++j) {
        long idx = base + j;
        v[j] = (idx < NNODES) ? deg[idx] : 0;
        s += v[j];
    }
    lds[t] = s;
    __syncthreads();
    for (int d = 1; d < 256; d <<= 1) {
        int x = (t >= d) ? lds[t - d] : 0;
        __syncthreads();
        lds[t] += x;
        __syncthreads();
    }
    int off = lds[t] - s;
    if (t == 255) bsum[blockIdx.x] = lds[255];
#pragma unroll
    for (int j = 0; j < 8; ++j) {
        long idx = base + j;
        if (idx < NNODES) rowptr[idx] = off;
        off += v[j];
    }
}

__global__ void scan2(int* __restrict__ bsum)
{
    __shared__ int lds[128];
    const int t = threadIdx.x;
    int v = (t < NSCANB) ? bsum[t] : 0;
    lds[t] = v;
    __syncthreads();
    for (int d = 1; d < 128; d <<= 1) {
        int x = (t >= d) ? lds[t - d] : 0;
        __syncthreads();
        lds[t] += x;
        __syncthreads();
    }
    if (t < NSCANB) bsum[t] = lds[t] - v;
}

__global__ void scan3(int* __restrict__ rowptr, const int* __restrict__ bsum,
                      int* __restrict__ cursor)
{
    long i = (long)blockIdx.x * 256 + threadIdx.x;
    if (i < NNODES) {
        int r = rowptr[i] + bsum[i / SCANB];
        rowptr[i] = r;
        cursor[i] = r;
    }
    if (i == 0) rowptr[NNODES] = NEDGES;
}

__global__ void fill_eidx(const int* __restrict__ src, const int* __restrict__ dst,
                          int* __restrict__ cursor, int* __restrict__ eidx)
{
    int e = blockIdx.x * 256 + threadIdx.x;
    if (e < NEDGES) {
        int pos = atomicAdd(&cursor[dst[e]], 1);
        eidx[pos] = src[e];
    }
}

// ---------------------------------------------------------------------------
// agg_fused: h[r] = FIRST ? HIN[r] : relu(bn3(Y[r])) + HIN[r]   (on the fly)
//            P[n] = (1+eps)*h[n] + sum_{m in N(n)} h[m]
// ---------------------------------------------------------------------------
template <bool FIRST>
__global__ __launch_bounds__(256) void agg_fused(
    const unsigned short* __restrict__ Y, const unsigned short* __restrict__ HIN,
    const float* __restrict__ st3, const float* __restrict__ g3,
    const float* __restrict__ b3, const int* __restrict__ rowptr,
    const int* __restrict__ eidx, const float* __restrict__ eps_gin, int layer,
    unsigned short* __restrict__ P)
{
    __shared__ float scb[128], shb[128];
    const int t = threadIdx.x;
    if (!FIRST) {
        if (t < 128) {
            float m = st3[t] * INV_N;
            float v = st3[128 + t] * INV_N - m * m;
            float s = g3[t] * rsqrtf(v + 1e-5f);
            scb[t] = s; shb[t] = b3[t] - m * s;
        }
        __syncthreads();
    }
    const int l16 = t & 15;
    const long n = (long)blockIdx.x * 16 + (t >> 4);
    const int c8 = l16 * 8;
    float sc[8], sh[8];
    if (!FIRST) {
#pragma unroll
        for (int j = 0; j < 8; ++j) { sc[j] = scb[c8 + j]; sh[j] = shb[c8 + j]; }
    }
    const float s = 1.0f + eps_gin[layer];
    float acc[8];
    {
        bf16x8 hv = *(const bf16x8*)&HIN[n * HDIM + c8];
        if (FIRST) {
#pragma unroll
            for (int j = 0; j < 8; ++j) acc[j] = s * b2f((unsigned short)hv[j]);
        } else {
            bf16x8 yv = *(const bf16x8*)&Y[n * HDIM + c8];
#pragma unroll
            for (int j = 0; j < 8; ++j)
                acc[j] = s * (relu_f(fmaf(b2f((unsigned short)yv[j]), sc[j], sh[j]))
                              + b2f((unsigned short)hv[j]));
        }
    }
    const int bg = rowptr[n], en = rowptr[n + 1];
    for (int i = bg; i < en; ++i) {
        long m = eidx[i];
        bf16x8 hv = *(const bf16x8*)&HIN[m * HDIM + c8];
        if (FIRST) {
#pragma unroll
            for (int j = 0; j < 8; ++j) acc[j] += b2f((unsigned short)hv[j]);
        } else {
            bf16x8 yv = *(const bf16x8*)&Y[m * HDIM + c8];
#pragma unroll
            for (int j = 0; j < 8; ++j)
                acc[j] += relu_f(fmaf(b2f((unsigned short)yv[j]), sc[j], sh[j]))
                          + b2f((unsigned short)hv[j]);
        }
    }
    bf16x8 o;
#pragma unroll
    for (int j = 0; j < 8; ++j) o[j] = (short)f2b(acc[j]);
    *(bf16x8*)&P[n * HDIM + c8] = o;
}

// ---------------------------------------------------------------------------
// x3: P = relu(bn2(P)) * snorm (in place), stats of result (pre-round f32)
// ---------------------------------------------------------------------------
__global__ __launch_bounds__(256) void x3_kernel(
    unsigned short* __restrict__ P, const float* __restrict__ st2,
    const float* __restrict__ g2, const float* __restrict__ b2v,
    const float* __restrict__ snorm, float* __restrict__ st3)
{
    __shared__ float scb[128], shb[128];
    __shared__ float red[16 * 132];
    const int t = threadIdx.x;
    if (t < 128) {
        float m = st2[t] * INV_N;
        float v = st2[128 + t] * INV_N - m * m;
        float s = g2[t] * rsqrtf(v + 1e-5f);
        scb[t] = s; shb[t] = b2v[t] - m * s;
    }
    __syncthreads();
    const int l16 = t & 15, g = t >> 4;
    const int c8 = l16 * 8;
    const long row0 = (long)blockIdx.x * 64 + g * 4;
    float sc[8], sh[8];
#pragma unroll
    for (int j = 0; j < 8; ++j) { sc[j] = scb[c8 + j]; sh[j] = shb[c8 + j]; }
    float sum[8] = {0, 0, 0, 0, 0, 0, 0, 0}, sq[8] = {0, 0, 0, 0, 0, 0, 0, 0};
#pragma unroll
    for (int rr = 0; rr < 4; ++rr) {
        long row = row0 + rr;
        float sn = snorm[row];
        bf16x8 v = *(const bf16x8*)&P[row * HDIM + c8];
        bf16x8 o;
#pragma unroll
        for (int j = 0; j < 8; ++j) {
            float x = b2f((unsigned short)v[j]);
            x = relu_f(fmaf(x, sc[j], sh[j])) * sn;
            o[j] = (short)f2b(x);
            sum[j] += x; sq[j] += x * x;
        }
        *(bf16x8*)&P[row * HDIM + c8] = o;
    }
#pragma unroll
    for (int j = 0; j < 8; ++j) red[g * 132 + c8 + j] = sum[j];
    __syncthreads();
    if (t < 128) {
        float s = 0;
#pragma unroll
        for (int gg = 0; gg < 16; ++gg) s += red[gg * 132 + t];
        atomicAdd(&st3[t], s);
    }
    __syncthreads();
#pragma unroll
    for (int j = 0; j < 8; ++j) red[g * 132 + c8 + j] = sq[j];
    __syncthreads();
    if (t < 128) {
        float s = 0;
#pragma unroll
        for (int gg = 0; gg < 16; ++gg) s += red[gg * 132 + t];
        atomicAdd(&st3[128 + t], s);
    }
}

// last layer: d[n] = (relu(bn3(Y[n])) + HIN[n]) . v ; gsum[gid[n]] += d[n]
__global__ __launch_bounds__(256) void fin_last(
    const unsigned short* __restrict__ Y, const unsigned short* __restrict__ HIN,
    const float* __restrict__ st3, const float* __restrict__ g3,
    const float* __restrict__ b3, const float* __restrict__ vvec,
    const int* __restrict__ gid, float* __restrict__ gsum)
{
    __shared__ float scb[128], shb[128];
    const int t = threadIdx.x;
    if (t < 128) {
        float m = st3[t] * INV_N;
        float va = st3[128 + t] * INV_N - m * m;
        float s = g3[t] * rsqrtf(va + 1e-5f);
        scb[t] = s; shb[t] = b3[t] - m * s;
    }
    __syncthreads();
    const int l16 = t & 15;
    const long n = (long)blockIdx.x * 16 + (t >> 4);
    const int c8 = l16 * 8;
    bf16x8 yv = *(const bf16x8*)&Y[n * HDIM + c8];
    bf16x8 hv = *(const bf16x8*)&HIN[n * HDIM + c8];
    float d = 0;
#pragma unroll
    for (int j = 0; j < 8; ++j) {
        float h = relu_f(fmaf(b2f((unsigned short)yv[j]), scb[c8 + j], shb[c8 + j]))
                  + b2f((unsigned short)hv[j]);
        d += h * vvec[c8 + j];
    }
#pragma unroll
    for (int off = 8; off > 0; off >>= 1) d += __shfl_down(d, off, 16);
    if (l16 == 0) atomicAdd(&gsum[gid[n]], d);
}

__global__ void gcnt_kernel(const int* __restrict__ gid, float* __restrict__ gcnt)
{
    int n = blockIdx.x * 256 + threadIdx.x;
    if (n < NNODES) atomicAdd(&gcnt[gid[n]], 1.0f);
}

__global__ void v_kernel(const float* __restrict__ W_ro, const float* __restrict__ W_pred,
                         float* __restrict__ v)
{
    int t = threadIdx.x;
    if (t < HDIM) {
        float s = 0;
        for (int j = 0; j < HDIM; ++j) s += W_ro[t * HDIM + j] * W_pred[j];
        v[t] = s;
    }
}

__global__ void score_kernel(const float* __restrict__ gsum, const float* __restrict__ gcnt,
                             const float* __restrict__ b_pred, float* __restrict__ out)
{
    int g = blockIdx.x * 256 + threadIdx.x;
    if (g < NGRAPH) out[g] = gsum[g] / fmaxf(gcnt[g], 1.0f) + b_pred[0];
}

extern "C" void kernel_launch(void* const* d_in, const int* in_sizes, int n_in,
                              void* d_out, int out_size, void* d_ws, size_t ws_size,
                              hipStream_t stream)
{
    const float* h_raw   = (const float*)d_in[0];
    const int*   src     = (const int*)d_in[1];
    const int*   dst     = (const int*)d_in[2];
    const int*   gid     = (const int*)d_in[3];
    const float* snorm   = (const float*)d_in[4];
    const float* W_emb   = (const float*)d_in[5];
    const float* eps_gin = (const float*)d_in[6];
    const float* W1      = (const float*)d_in[7];
    const float* b1      = (const float*)d_in[8];
    const float* bn1_g   = (const float*)d_in[9];
    const float* bn1_b   = (const float*)d_in[10];
    const float* W2      = (const float*)d_in[11];
    const float* b2      = (const float*)d_in[12];
    const float* bn2_g   = (const float*)d_in[13];
    const float* bn2_b   = (const float*)d_in[14];
    const float* bn3_g   = (const float*)d_in[15];
    const float* bn3_b   = (const float*)d_in[16];
    const float* W_ro    = (const float*)d_in[17];
    const float* W_pred  = (const float*)d_in[18];
    const float* b_pred  = (const float*)d_in[19];
    float* out = (float*)d_out;

    const size_t NH = (size_t)NNODES * HDIM;      // elements per [N,128]
    unsigned short* HIN = (unsigned short*)d_ws;
    unsigned short* Pa  = HIN + NH;
    unsigned short* Pb  = Pa + NH;
    float* Z      = (float*)(Pb + NH);
    float* statsb = Z;                  // 12 * 256
    float* gsum   = Z + 12 * 256;       // 8000
    float* gcnt   = gsum + NGRAPH;      // 8000
    float* vvec   = gcnt + NGRAPH;      // 128
    int* rowptr = (int*)(vvec + 128);          // N+1
    int* deg    = rowptr + NNODES + 1;         // N (becomes Wtb after scan1)
    int* cursor = deg + NNODES;                // N
    int* bsum   = cursor + NNODES;             // 128
    int* eidx   = bsum + 128;                  // E
    unsigned short* Wtb =
        (unsigned short*)(((uintptr_t)deg + 15) & ~(uintptr_t)15);  // 9*16384 u16

    hipMemsetAsync(Z, 0, 19072 * sizeof(float), stream);
    hipMemsetAsync(deg, 0, NNODES * sizeof(int), stream);

    gcnt_kernel<<<(NNODES + 255) / 256, 256, 0, stream>>>(gid, gcnt);
    v_kernel<<<1, 128, 0, stream>>>(W_ro, W_pred, vvec);

    // CSR build (deg consumed by scan1, then its space becomes Wtb)
    deg_kernel<<<(NEDGES + 255) / 256, 256, 0, stream>>>(dst, deg);
    scan1<<<NSCANB, 256, 0, stream>>>(deg, rowptr, bsum);
    scan2<<<1, 128, 0, stream>>>(bsum);
    scan3<<<(NNODES + 255) / 256, 256, 0, stream>>>(rowptr, bsum, cursor);
    fill_eidx<<<(NEDGES + 255) / 256, 256, 0, stream>>>(src, dst, cursor, eidx);

    // weights -> bf16 transposed [9][128][128]
    wconv<<<(9 * 16384) / 256, 256, 0, stream>>>(W_emb, W1, W2, Wtb);

    // embedding: HIN = bf16(h_raw @ W_emb)
    gemm_mfma<true, false, false><<<NNODES / 64, 256, 0, stream>>>(
        h_raw, Wtb, nullptr, nullptr, nullptr, nullptr, HIN, nullptr);

    unsigned short* bufs[2] = {Pa, Pb};
    int cur = 0;
    for (int i = 0; i < NLAYER; ++i) {
        float* st1 = statsb + (i * 3 + 0) * 256;
        float* st2 = statsb + (i * 3 + 1) * 256;
        float* st3 = statsb + (i * 3 + 2) * 256;

        if (i == 0) {
            agg_fused<true><<<NNODES / 16, 256, 0, stream>>>(
                nullptr, HIN, nullptr, nullptr, nullptr,
                rowptr, eidx, eps_gin, 0, bufs[0]);
            cur = 0;
        } else {
            int nxt = cur ^ 1;
            float* st3p = statsb + ((i - 1) * 3 + 2) * 256;
            agg_fused<false><<<NNODES / 16, 256, 0, stream>>>(
                bufs[cur], HIN, st3p, bn3_g + (i - 1) * HDIM, bn3_b + (i - 1) * HDIM,
                rowptr, eidx, eps_gin, i, bufs[nxt]);
            cur = nxt;
        }
        unsigned short* B = bufs[cur];

        gemm_mfma<false, false, true><<<NNODES / 64, 256, 0, stream>>>(
            B, Wtb + (size_t)(1 + i) * 16384, b1 + i * HDIM,
            nullptr, nullptr, nullptr, B, st1);
        gemm_mfma<false, true, true><<<NNODES / 64, 256, 0, stream>>>(
            B, Wtb + (size_t)(5 + i) * 16384, b2 + i * HDIM,
            st1, bn1_g + i * HDIM, bn1_b + i * HDIM, B, st2);
        x3_kernel<<<NNODES / 64, 256, 0, stream>>>(
            B, st2, bn2_g + i * HDIM, bn2_b + i * HDIM, snorm, st3);
    }

    fin_last<<<NNODES / 16, 256, 0, stream>>>(
        bufs[cur], HIN, statsb + (3 * 3 + 2) * 256,
        bn3_g + 3 * HDIM, bn3_b + 3 * HDIM, vvec, gid, gsum);
    score_kernel<<<(NGRAPH + 255) / 256, 256, 0, stream>>>(gsum, gcnt, b_pred, out);
}

// Round 6
// 1136.134 us; speedup vs baseline: 4.4673x; 1.3002x over previous
//
#include <hip/hip_runtime.h>

#define NNODES 200000
#define NEDGES 400000
#define NGRAPH 8000
#define ADIM 100
#define HDIM 128
#define NLAYER 4
#define SCANB 2048
#define NSCANB ((NNODES + SCANB - 1) / SCANB)   // 98
#define INV_N (1.0f / (float)NNODES)
#define GTILES 5                                 // row-tiles (64) per gemm block
#define GROWS (64 * GTILES)                      // 320 rows per block
#define GGRID (NNODES / GROWS)                   // 625 blocks

typedef float4 f4;
typedef __attribute__((ext_vector_type(8))) short bf16x8;
typedef __attribute__((ext_vector_type(4))) float f32x4;

__device__ __forceinline__ float relu_f(float x) { return fmaxf(x, 0.0f); }

// f32 -> bf16 (RNE)
__device__ __forceinline__ unsigned short f2b(float x)
{
    unsigned int u = __float_as_uint(x);
    u = (u + 0x7FFFu + ((u >> 16) & 1u)) >> 16;
    return (unsigned short)u;
}
__device__ __forceinline__ float b2f(unsigned short b)
{
    return __uint_as_float(((unsigned int)b) << 16);
}

// ---------------------------------------------------------------------------
// Weight convert into MFMA B-fragment order:
// Wtb[m][f][ks][l][j] = bf16(W_m[k][n]), n = 16f + (l&15), k = 32ks + 8(l>>4) + j
// so a wave's B-fragment read is Wl[(4f+ks)*512 + l*8] : conflict-free, coalesced.
// ---------------------------------------------------------------------------
__global__ void wconv(const float* __restrict__ W_emb, const float* __restrict__ W1,
                      const float* __restrict__ W2, unsigned short* __restrict__ Wtb)
{
    int id = blockIdx.x * 256 + threadIdx.x;   // 9*16384 total
    int m = id >> 14;
    int r = id & 16383;
    int j  = r & 7;
    int l  = (r >> 3) & 63;
    int ks = (r >> 9) & 3;
    int f  = r >> 11;
    int n = 16 * f + (l & 15);
    int k = 32 * ks + 8 * (l >> 4) + j;
    float v;
    if (m == 0)      v = (k < ADIM) ? W_emb[k * HDIM + n] : 0.0f;
    else if (m <= 4) v = W1[(size_t)(m - 1) * HDIM * HDIM + k * HDIM + n];
    else             v = W2[(size_t)(m - 5) * HDIM * HDIM + k * HDIM + n];
    Wtb[id] = f2b(v);
}

// ---------------------------------------------------------------------------
// MFMA GEMM: C[N,128] = f(A) @ W (+bias), optional col stats.
// Block = GTILES x (64 rows), 4 waves x 16 rows per tile. W staged once per
// block (fragment-order, conflict-free). A fragments loaded directly from
// global (bf16 layout == fragment layout). Stats accumulated in registers
// across tiles; one reduction per block. In-place safe (disjoint rows).
// ---------------------------------------------------------------------------
template <bool EMB, bool APPLY, bool STATS>
__global__ __launch_bounds__(256, 3) void gemm_mfma(
    const void* __restrict__ Av, const unsigned short* __restrict__ Wt,
    const float* __restrict__ bias, const float* __restrict__ stIn,
    const float* __restrict__ gIn, const float* __restrict__ bIn,
    unsigned short* __restrict__ C, float* __restrict__ stOut)
{
    __shared__ unsigned short Wl[16384];
    __shared__ float red[STATS ? 4 * 258 : 1];
    __shared__ float scb[APPLY ? 128 : 1];
    __shared__ float shb[APPLY ? 128 : 1];

    const int t = threadIdx.x;

    if (APPLY && t < 128) {
        float m = stIn[t] * INV_N;
        float v = stIn[128 + t] * INV_N - m * m;
        float s = gIn[t] * rsqrtf(v + 1e-5f);
        scb[t] = s; shb[t] = bIn[t] - m * s;
    }
    // stage W (32 KB) once, coalesced, conflict-free
    for (int idx = t; idx < 2048; idx += 256)
        *(bf16x8*)&Wl[idx * 8] = *(const bf16x8*)&Wt[idx * 8];
    __syncthreads();

    const int w = t >> 6, l = t & 63;
    const int lr = l & 15, lk = l >> 4;
    const long rowBase = (long)blockIdx.x * GROWS;

    float psum[8], psq[8];
#pragma unroll
    for (int f = 0; f < 8; ++f) { psum[f] = 0.f; psq[f] = 0.f; }
    float bv[8];
#pragma unroll
    for (int f = 0; f < 8; ++f) bv[f] = STATS ? bias[16 * f + lr] : 0.0f;

#pragma unroll
    for (int tile = 0; tile < GTILES; ++tile) {
        const long arow = rowBase + tile * 64 + 16 * w + lr;

        bf16x8 af[4];
        if (EMB) {
            const float* A = (const float*)Av;
#pragma unroll
            for (int ks = 0; ks < 4; ++ks) {
                int k0 = ks * 32 + lk * 8;
                f4 a0 = {0, 0, 0, 0}, a1 = {0, 0, 0, 0};
                if (k0 < ADIM)      a0 = *(const f4*)&A[arow * ADIM + k0];
                if (k0 + 8 <= ADIM) a1 = *(const f4*)&A[arow * ADIM + k0 + 4];
                bf16x8 v;
                v[0] = (short)f2b(a0.x); v[1] = (short)f2b(a0.y);
                v[2] = (short)f2b(a0.z); v[3] = (short)f2b(a0.w);
                v[4] = (short)f2b(a1.x); v[5] = (short)f2b(a1.y);
                v[6] = (short)f2b(a1.z); v[7] = (short)f2b(a1.w);
                af[ks] = v;
            }
        } else {
            const unsigned short* A = (const unsigned short*)Av;
#pragma unroll
            for (int ks = 0; ks < 4; ++ks)
                af[ks] = *(const bf16x8*)&A[arow * HDIM + ks * 32 + lk * 8];
            if (APPLY) {
#pragma unroll
                for (int ks = 0; ks < 4; ++ks) {
                    int k0 = ks * 32 + lk * 8;
                    bf16x8 v = af[ks];
#pragma unroll
                    for (int j = 0; j < 8; ++j) {
                        float x = b2f((unsigned short)v[j]);
                        x = relu_f(fmaf(x, scb[k0 + j], shb[k0 + j]));
                        v[j] = (short)f2b(x);
                    }
                    af[ks] = v;
                }
            }
        }

        f32x4 acc[8];
#pragma unroll
        for (int f = 0; f < 8; ++f) acc[f] = (f32x4){0.f, 0.f, 0.f, 0.f};
#pragma unroll
        for (int ks = 0; ks < 4; ++ks) {
#pragma unroll
            for (int f = 0; f < 8; ++f) {
                bf16x8 bfr = *(const bf16x8*)&Wl[(f * 4 + ks) * 512 + l * 8];
                acc[f] = __builtin_amdgcn_mfma_f32_16x16x32_bf16(af[ks], bfr, acc[f], 0, 0, 0);
            }
        }

#pragma unroll
        for (int f = 0; f < 8; ++f) {
#pragma unroll
            for (int r = 0; r < 4; ++r) {
                float val = acc[f][r] + bv[f];
                C[(rowBase + tile * 64 + 16 * w + lk * 4 + r) * HDIM + 16 * f + lr] = f2b(val);
                if (STATS) { psum[f] += val; psq[f] += val * val; }
            }
        }
    }

    if (STATS) {
        // reduce across the 4 lk-groups of the wave (same columns)
#pragma unroll
        for (int f = 0; f < 8; ++f) {
            psum[f] += __shfl_xor(psum[f], 16, 64);
            psum[f] += __shfl_xor(psum[f], 32, 64);
            psq[f]  += __shfl_xor(psq[f], 16, 64);
            psq[f]  += __shfl_xor(psq[f], 32, 64);
        }
        if (lk == 0) {
#pragma unroll
            for (int f = 0; f < 8; ++f) {
                red[w * 258 + 16 * f + lr]       = psum[f];
                red[w * 258 + 128 + 16 * f + lr] = psq[f];
            }
        }
        __syncthreads();
        if (t < 256) {
            float s = red[t] + red[258 + t] + red[2 * 258 + t] + red[3 * 258 + t];
            atomicAdd(&stOut[t], s);
        }
    }
}

// ---------------- CSR build (graph static per call) -------------------------
__global__ void deg_kernel(const int* __restrict__ dst, int* __restrict__ deg)
{
    int e = blockIdx.x * 256 + threadIdx.x;
    if (e < NEDGES) atomicAdd(&deg[dst[e]], 1);
}

__global__ __launch_bounds__(256) void scan1(const int* __restrict__ deg,
                                             int* __restrict__ rowptr,
                                             int* __restrict__ bsum)
{
    __shared__ int lds[256];
    const int t = threadIdx.x;
    const long base = (long)blockIdx.x * SCANB + t * 8;
    int v[8];
    int s = 0;
#pragma unroll
    for (int j = 0; j < 8; ++j) {
        long idx = base + j;
        v[j] = (idx < NNODES) ? deg[idx] : 0;
        s += v[j];
    }
    lds[t] = s;
    __syncthreads();
    for (int d = 1; d < 256; d <<= 1) {
        int x = (t >= d) ? lds[t - d] : 0;
        __syncthreads();
        lds[t] += x;
        __syncthreads();
    }
    int off = lds[t] - s;
    if (t == 255) bsum[blockIdx.x] = lds[255];
#pragma unroll
    for (int j = 0; j < 8; ++j) {
        long idx = base + j;
        if (idx < NNODES) rowptr[idx] = off;
        off += v[j];
    }
}

__global__ void scan2(int* __restrict__ bsum)
{
    __shared__ int lds[128];
    const int t = threadIdx.x;
    int v = (t < NSCANB) ? bsum[t] : 0;
    lds[t] = v;
    __syncthreads();
    for (int d = 1; d < 128; d <<= 1) {
        int x = (t >= d) ? lds[t - d] : 0;
        __syncthreads();
        lds[t] += x;
        __syncthreads();
    }
    if (t < NSCANB) bsum[t] = lds[t] - v;
}

__global__ void scan3(int* __restrict__ rowptr, const int* __restrict__ bsum,
                      int* __restrict__ cursor)
{
    long i = (long)blockIdx.x * 256 + threadIdx.x;
    if (i < NNODES) {
        int r = rowptr[i] + bsum[i / SCANB];
        rowptr[i] = r;
        cursor[i] = r;
    }
    if (i == 0) rowptr[NNODES] = NEDGES;
}

__global__ void fill_eidx(const int* __restrict__ src, const int* __restrict__ dst,
                          int* __restrict__ cursor, int* __restrict__ eidx)
{
    int e = blockIdx.x * 256 + threadIdx.x;
    if (e < NEDGES) {
        int pos = atomicAdd(&cursor[dst[e]], 1);
        eidx[pos] = src[e];
    }
}

// ---------------------------------------------------------------------------
// agg_fused: h[r] = FIRST ? HIN[r] : relu(bn3(Y[r])) + HIN[r]   (on the fly)
//            P[n] = (1+eps)*h[n] + sum_{m in N(n)} h[m]
// ---------------------------------------------------------------------------
template <bool FIRST>
__global__ __launch_bounds__(256) void agg_fused(
    const unsigned short* __restrict__ Y, const unsigned short* __restrict__ HIN,
    const float* __restrict__ st3, const float* __restrict__ g3,
    const float* __restrict__ b3, const int* __restrict__ rowptr,
    const int* __restrict__ eidx, const float* __restrict__ eps_gin, int layer,
    unsigned short* __restrict__ P)
{
    __shared__ float scb[128], shb[128];
    const int t = threadIdx.x;
    if (!FIRST) {
        if (t < 128) {
            float m = st3[t] * INV_N;
            float v = st3[128 + t] * INV_N - m * m;
            float s = g3[t] * rsqrtf(v + 1e-5f);
            scb[t] = s; shb[t] = b3[t] - m * s;
        }
        __syncthreads();
    }
    const int l16 = t & 15;
    const long n = (long)blockIdx.x * 16 + (t >> 4);
    const int c8 = l16 * 8;
    float sc[8], sh[8];
    if (!FIRST) {
#pragma unroll
        for (int j = 0; j < 8; ++j) { sc[j] = scb[c8 + j]; sh[j] = shb[c8 + j]; }
    }
    const float s = 1.0f + eps_gin[layer];
    float acc[8];
    {
        bf16x8 hv = *(const bf16x8*)&HIN[n * HDIM + c8];
        if (FIRST) {
#pragma unroll
            for (int j = 0; j < 8; ++j) acc[j] = s * b2f((unsigned short)hv[j]);
        } else {
            bf16x8 yv = *(const bf16x8*)&Y[n * HDIM + c8];
#pragma unroll
            for (int j = 0; j < 8; ++j)
                acc[j] = s * (relu_f(fmaf(b2f((unsigned short)yv[j]), sc[j], sh[j]))
                              + b2f((unsigned short)hv[j]));
        }
    }
    const int bg = rowptr[n], en = rowptr[n + 1];
    for (int i = bg; i < en; ++i) {
        long m = eidx[i];
        bf16x8 hv = *(const bf16x8*)&HIN[m * HDIM + c8];
        if (FIRST) {
#pragma unroll
            for (int j = 0; j < 8; ++j) acc[j] += b2f((unsigned short)hv[j]);
        } else {
            bf16x8 yv = *(const bf16x8*)&Y[m * HDIM + c8];
#pragma unroll
            for (int j = 0; j < 8; ++j)
                acc[j] += relu_f(fmaf(b2f((unsigned short)yv[j]), sc[j], sh[j]))
                          + b2f((unsigned short)hv[j]);
        }
    }
    bf16x8 o;
#pragma unroll
    for (int j = 0; j < 8; ++j) o[j] = (short)f2b(acc[j]);
    *(bf16x8*)&P[n * HDIM + c8] = o;
}

// ---------------------------------------------------------------------------
// x3: P = relu(bn2(P)) * snorm (in place), stats of result (pre-round f32)
// ---------------------------------------------------------------------------
__global__ __launch_bounds__(256) void x3_kernel(
    unsigned short* __restrict__ P, const float* __restrict__ st2,
    const float* __restrict__ g2, const float* __restrict__ b2v,
    const float* __restrict__ snorm, float* __restrict__ st3)
{
    __shared__ float scb[128], shb[128];
    __shared__ float red[16 * 132];
    const int t = threadIdx.x;
    if (t < 128) {
        float m = st2[t] * INV_N;
        float v = st2[128 + t] * INV_N - m * m;
        float s = g2[t] * rsqrtf(v + 1e-5f);
        scb[t] = s; shb[t] = b2v[t] - m * s;
    }
    __syncthreads();
    const int l16 = t & 15, g = t >> 4;
    const int c8 = l16 * 8;
    const long row0 = (long)blockIdx.x * 64 + g * 4;
    float sc[8], sh[8];
#pragma unroll
    for (int j = 0; j < 8; ++j) { sc[j] = scb[c8 + j]; sh[j] = shb[c8 + j]; }
    float sum[8] = {0, 0, 0, 0, 0, 0, 0, 0}, sq[8] = {0, 0, 0, 0, 0, 0, 0, 0};
#pragma unroll
    for (int rr = 0; rr < 4; ++rr) {
        long row = row0 + rr;
        float sn = snorm[row];
        bf16x8 v = *(const bf16x8*)&P[row * HDIM + c8];
        bf16x8 o;
#pragma unroll
        for (int j = 0; j < 8; ++j) {
            float x = b2f((unsigned short)v[j]);
            x = relu_f(fmaf(x, sc[j], sh[j])) * sn;
            o[j] = (short)f2b(x);
            sum[j] += x; sq[j] += x * x;
        }
        *(bf16x8*)&P[row * HDIM + c8] = o;
    }
#pragma unroll
    for (int j = 0; j < 8; ++j) red[g * 132 + c8 + j] = sum[j];
    __syncthreads();
    if (t < 128) {
        float s = 0;
#pragma unroll
        for (int gg = 0; gg < 16; ++gg) s += red[gg * 132 + t];
        atomicAdd(&st3[t], s);
    }
    __syncthreads();
#pragma unroll
    for (int j = 0; j < 8; ++j) red[g * 132 + c8 + j] = sq[j];
    __syncthreads();
    if (t < 128) {
        float s = 0;
#pragma unroll
        for (int gg = 0; gg < 16; ++gg) s += red[gg * 132 + t];
        atomicAdd(&st3[128 + t], s);
    }
}

// last layer: d[n] = (relu(bn3(Y[n])) + HIN[n]) . v ; gsum[gid[n]] += d[n]
__global__ __launch_bounds__(256) void fin_last(
    const unsigned short* __restrict__ Y, const unsigned short* __restrict__ HIN,
    const float* __restrict__ st3, const float* __restrict__ g3,
    const float* __restrict__ b3, const float* __restrict__ vvec,
    const int* __restrict__ gid, float* __restrict__ gsum)
{
    __shared__ float scb[128], shb[128];
    const int t = threadIdx.x;
    if (t < 128) {
        float m = st3[t] * INV_N;
        float va = st3[128 + t] * INV_N - m * m;
        float s = g3[t] * rsqrtf(va + 1e-5f);
        scb[t] = s; shb[t] = b3[t] - m * s;
    }
    __syncthreads();
    const int l16 = t & 15;
    const long n = (long)blockIdx.x * 16 + (t >> 4);
    const int c8 = l16 * 8;
    bf16x8 yv = *(const bf16x8*)&Y[n * HDIM + c8];
    bf16x8 hv = *(const bf16x8*)&HIN[n * HDIM + c8];
    float d = 0;
#pragma unroll
    for (int j = 0; j < 8; ++j) {
        float h = relu_f(fmaf(b2f((unsigned short)yv[j]), scb[c8 + j], shb[c8 + j]))
                  + b2f((unsigned short)hv[j]);
        d += h * vvec[c8 + j];
    }
#pragma unroll
    for (int off = 8; off > 0; off >>= 1) d += __shfl_down(d, off, 16);
    if (l16 == 0) atomicAdd(&gsum[gid[n]], d);
}

__global__ void gcnt_kernel(const int* __restrict__ gid, float* __restrict__ gcnt)
{
    int n = blockIdx.x * 256 + threadIdx.x;
    if (n < NNODES) atomicAdd(&gcnt[gid[n]], 1.0f);
}

__global__ void v_kernel(const float* __restrict__ W_ro, const float* __restrict__ W_pred,
                         float* __restrict__ v)
{
    int t = threadIdx.x;
    if (t < HDIM) {
        float s = 0;
        for (int j = 0; j < HDIM; ++j) s += W_ro[t * HDIM + j] * W_pred[j];
        v[t] = s;
    }
}

__global__ void score_kernel(const float* __restrict__ gsum, const float* __restrict__ gcnt,
                             const float* __restrict__ b_pred, float* __restrict__ out)
{
    int g = blockIdx.x * 256 + threadIdx.x;
    if (g < NGRAPH) out[g] = gsum[g] / fmaxf(gcnt[g], 1.0f) + b_pred[0];
}

extern "C" void kernel_launch(void* const* d_in, const int* in_sizes, int n_in,
                              void* d_out, int out_size, void* d_ws, size_t ws_size,
                              hipStream_t stream)
{
    const float* h_raw   = (const float*)d_in[0];
    const int*   src     = (const int*)d_in[1];
    const int*   dst     = (const int*)d_in[2];
    const int*   gid     = (const int*)d_in[3];
    const float* snorm   = (const float*)d_in[4];
    const float* W_emb   = (const float*)d_in[5];
    const float* eps_gin = (const float*)d_in[6];
    const float* W1      = (const float*)d_in[7];
    const float* b1      = (const float*)d_in[8];
    const float* bn1_g   = (const float*)d_in[9];
    const float* bn1_b   = (const float*)d_in[10];
    const float* W2      = (const float*)d_in[11];
    const float* b2      = (const float*)d_in[12];
    const float* bn2_g   = (const float*)d_in[13];
    const float* bn2_b   = (const float*)d_in[14];
    const float* bn3_g   = (const float*)d_in[15];
    const float* bn3_b   = (const float*)d_in[16];
    const float* W_ro    = (const float*)d_in[17];
    const float* W_pred  = (const float*)d_in[18];
    const float* b_pred  = (const float*)d_in[19];
    float* out = (float*)d_out;

    const size_t NH = (size_t)NNODES * HDIM;      // elements per [N,128]
    unsigned short* HIN = (unsigned short*)d_ws;
    unsigned short* Pa  = HIN + NH;
    unsigned short* Pb  = Pa + NH;
    float* Z      = (float*)(Pb + NH);
    float* statsb = Z;                  // 12 * 256
    float* gsum   = Z + 12 * 256;       // 8000
    float* gcnt   = gsum + NGRAPH;      // 8000
    float* vvec   = gcnt + NGRAPH;      // 128
    int* rowptr = (int*)(vvec + 128);          // N+1
    int* deg    = rowptr + NNODES + 1;         // N (becomes Wtb after scan1)
    int* cursor = deg + NNODES;                // N
    int* bsum   = cursor + NNODES;             // 128
    int* eidx   = bsum + 128;                  // E
    unsigned short* Wtb =
        (unsigned short*)(((uintptr_t)deg + 15) & ~(uintptr_t)15);  // 9*16384 u16

    hipMemsetAsync(Z, 0, 19072 * sizeof(float), stream);
    hipMemsetAsync(deg, 0, NNODES * sizeof(int), stream);

    gcnt_kernel<<<(NNODES + 255) / 256, 256, 0, stream>>>(gid, gcnt);
    v_kernel<<<1, 128, 0, stream>>>(W_ro, W_pred, vvec);

    // CSR build (deg consumed by scan1, then its space becomes Wtb)
    deg_kernel<<<(NEDGES + 255) / 256, 256, 0, stream>>>(dst, deg);
    scan1<<<NSCANB, 256, 0, stream>>>(deg, rowptr, bsum);
    scan2<<<1, 128, 0, stream>>>(bsum);
    scan3<<<(NNODES + 255) / 256, 256, 0, stream>>>(rowptr, bsum, cursor);
    fill_eidx<<<(NEDGES + 255) / 256, 256, 0, stream>>>(src, dst, cursor, eidx);

    // weights -> bf16 fragment-order [9][8][4][64][8]
    wconv<<<(9 * 16384) / 256, 256, 0, stream>>>(W_emb, W1, W2, Wtb);

    // embedding: HIN = bf16(h_raw @ W_emb)
    gemm_mfma<true, false, false><<<GGRID, 256, 0, stream>>>(
        h_raw, Wtb, nullptr, nullptr, nullptr, nullptr, HIN, nullptr);

    unsigned short* bufs[2] = {Pa, Pb};
    int cur = 0;
    for (int i = 0; i < NLAYER; ++i) {
        float* st1 = statsb + (i * 3 + 0) * 256;
        float* st2 = statsb + (i * 3 + 1) * 256;
        float* st3 = statsb + (i * 3 + 2) * 256;

        if (i == 0) {
            agg_fused<true><<<NNODES / 16, 256, 0, stream>>>(
                nullptr, HIN, nullptr, nullptr, nullptr,
                rowptr, eidx, eps_gin, 0, bufs[0]);
            cur = 0;
        } else {
            int nxt = cur ^ 1;
            float* st3p = statsb + ((i - 1) * 3 + 2) * 256;
            agg_fused<false><<<NNODES / 16, 256, 0, stream>>>(
                bufs[cur], HIN, st3p, bn3_g + (i - 1) * HDIM, bn3_b + (i - 1) * HDIM,
                rowptr, eidx, eps_gin, i, bufs[nxt]);
            cur = nxt;
        }
        unsigned short* B = bufs[cur];

        gemm_mfma<false, false, true><<<GGRID, 256, 0, stream>>>(
            B, Wtb + (size_t)(1 + i) * 16384, b1 + i * HDIM,
            nullptr, nullptr, nullptr, B, st1);
        gemm_mfma<false, true, true><<<GGRID, 256, 0, stream>>>(
            B, Wtb + (size_t)(5 + i) * 16384, b2 + i * HDIM,
            st1, bn1_g + i * HDIM, bn1_b + i * HDIM, B, st2);
        x3_kernel<<<NNODES / 64, 256, 0, stream>>>(
            B, st2, bn2_g + i * HDIM, bn2_b + i * HDIM, snorm, st3);
    }

    fin_last<<<NNODES / 16, 256, 0, stream>>>(
        bufs[cur], HIN, statsb + (3 * 3 + 2) * 256,
        bn3_g + 3 * HDIM, bn3_b + 3 * HDIM, vvec, gid, gsum);
    score_kernel<<<(NGRAPH + 255) / 256, 256, 0, stream>>>(gsum, gcnt, b_pred, out);
}

// Round 7
// 976.342 us; speedup vs baseline: 5.1984x; 1.1637x over previous
//
#include <hip/hip_runtime.h>

#define NNODES 200000
#define NEDGES 400000
#define NGRAPH 8000
#define ADIM 100
#define HDIM 128
#define NLAYER 4
#define SCANB 2048
#define NSCANB ((NNODES + SCANB - 1) / SCANB)   // 98
#define INV_N (1.0f / (float)NNODES)
#define GTILES 5                                 // row-tiles (64) per gemm block
#define GROWS (64 * GTILES)                      // 320 rows per block
#define GGRID (NNODES / GROWS)                   // 625 blocks
#define NTILES (NNODES / 64)                     // 3125
#define X3GRID 512

typedef float4 f4;
typedef __attribute__((ext_vector_type(8))) short bf16x8;
typedef __attribute__((ext_vector_type(4))) float f32x4;

__device__ __forceinline__ float relu_f(float x) { return fmaxf(x, 0.0f); }

// f32 -> bf16 (RNE)
__device__ __forceinline__ unsigned short f2b(float x)
{
    unsigned int u = __float_as_uint(x);
    u = (u + 0x7FFFu + ((u >> 16) & 1u)) >> 16;
    return (unsigned short)u;
}
__device__ __forceinline__ float b2f(unsigned short b)
{
    return __uint_as_float(((unsigned int)b) << 16);
}

// ---------------------------------------------------------------------------
// Weight convert into MFMA B-fragment order:
// Wtb[m][f][ks][l][j] = bf16(W_m[k][n]), n = 16f + (l&15), k = 32ks + 8(l>>4) + j
// so a wave's B-fragment read is Wl[(4f+ks)*512 + l*8] : conflict-free, coalesced.
// ---------------------------------------------------------------------------
__global__ void wconv(const float* __restrict__ W_emb, const float* __restrict__ W1,
                      const float* __restrict__ W2, unsigned short* __restrict__ Wtb)
{
    int id = blockIdx.x * 256 + threadIdx.x;   // 9*16384 total
    int m = id >> 14;
    int r = id & 16383;
    int j  = r & 7;
    int l  = (r >> 3) & 63;
    int ks = (r >> 9) & 3;
    int f  = r >> 11;
    int n = 16 * f + (l & 15);
    int k = 32 * ks + 8 * (l >> 4) + j;
    float v;
    if (m == 0)      v = (k < ADIM) ? W_emb[k * HDIM + n] : 0.0f;
    else if (m <= 4) v = W1[(size_t)(m - 1) * HDIM * HDIM + k * HDIM + n];
    else             v = W2[(size_t)(m - 5) * HDIM * HDIM + k * HDIM + n];
    Wtb[id] = f2b(v);
}

// ---------------------------------------------------------------------------
// MFMA GEMM: C[N,128] = f(A) @ W (+bias), optional col stats.
// Block = GTILES x (64 rows), 4 waves x 16 rows per tile. W staged once per
// block (fragment-order, conflict-free). A fragments loaded directly from
// global (bf16 layout == fragment layout). Stats accumulated in registers
// across tiles; one reduction per block. In-place safe (disjoint rows).
// ---------------------------------------------------------------------------
template <bool EMB, bool APPLY, bool STATS>
__global__ __launch_bounds__(256, 4) void gemm_mfma(
    const void* __restrict__ Av, const unsigned short* __restrict__ Wt,
    const float* __restrict__ bias, const float* __restrict__ stIn,
    const float* __restrict__ gIn, const float* __restrict__ bIn,
    unsigned short* __restrict__ C, float* __restrict__ stOut)
{
    __shared__ unsigned short Wl[16384];
    __shared__ float red[STATS ? 4 * 258 : 1];
    __shared__ float scb[APPLY ? 128 : 1];
    __shared__ float shb[APPLY ? 128 : 1];

    const int t = threadIdx.x;

    if (APPLY && t < 128) {
        float m = stIn[t] * INV_N;
        float v = stIn[128 + t] * INV_N - m * m;
        float s = gIn[t] * rsqrtf(v + 1e-5f);
        scb[t] = s; shb[t] = bIn[t] - m * s;
    }
    // stage W (32 KB) once, coalesced, conflict-free
    for (int idx = t; idx < 2048; idx += 256)
        *(bf16x8*)&Wl[idx * 8] = *(const bf16x8*)&Wt[idx * 8];
    __syncthreads();

    const int w = t >> 6, l = t & 63;
    const int lr = l & 15, lk = l >> 4;
    const long rowBase = (long)blockIdx.x * GROWS;

    float psum[8], psq[8];
#pragma unroll
    for (int f = 0; f < 8; ++f) { psum[f] = 0.f; psq[f] = 0.f; }
    float bv[8];
#pragma unroll
    for (int f = 0; f < 8; ++f) bv[f] = STATS ? bias[16 * f + lr] : 0.0f;

#pragma unroll
    for (int tile = 0; tile < GTILES; ++tile) {
        const long arow = rowBase + tile * 64 + 16 * w + lr;

        bf16x8 af[4];
        if (EMB) {
            const float* A = (const float*)Av;
#pragma unroll
            for (int ks = 0; ks < 4; ++ks) {
                int k0 = ks * 32 + lk * 8;
                f4 a0 = {0, 0, 0, 0}, a1 = {0, 0, 0, 0};
                if (k0 < ADIM)      a0 = *(const f4*)&A[arow * ADIM + k0];
                if (k0 + 8 <= ADIM) a1 = *(const f4*)&A[arow * ADIM + k0 + 4];
                bf16x8 v;
                v[0] = (short)f2b(a0.x); v[1] = (short)f2b(a0.y);
                v[2] = (short)f2b(a0.z); v[3] = (short)f2b(a0.w);
                v[4] = (short)f2b(a1.x); v[5] = (short)f2b(a1.y);
                v[6] = (short)f2b(a1.z); v[7] = (short)f2b(a1.w);
                af[ks] = v;
            }
        } else {
            const unsigned short* A = (const unsigned short*)Av;
#pragma unroll
            for (int ks = 0; ks < 4; ++ks)
                af[ks] = *(const bf16x8*)&A[arow * HDIM + ks * 32 + lk * 8];
            if (APPLY) {
#pragma unroll
                for (int ks = 0; ks < 4; ++ks) {
                    int k0 = ks * 32 + lk * 8;
                    bf16x8 v = af[ks];
#pragma unroll
                    for (int j = 0; j < 8; ++j) {
                        float x = b2f((unsigned short)v[j]);
                        x = relu_f(fmaf(x, scb[k0 + j], shb[k0 + j]));
                        v[j] = (short)f2b(x);
                    }
                    af[ks] = v;
                }
            }
        }

        f32x4 acc[8];
#pragma unroll
        for (int f = 0; f < 8; ++f) acc[f] = (f32x4){0.f, 0.f, 0.f, 0.f};
#pragma unroll
        for (int ks = 0; ks < 4; ++ks) {
#pragma unroll
            for (int f = 0; f < 8; ++f) {
                bf16x8 bfr = *(const bf16x8*)&Wl[(f * 4 + ks) * 512 + l * 8];
                acc[f] = __builtin_amdgcn_mfma_f32_16x16x32_bf16(af[ks], bfr, acc[f], 0, 0, 0);
            }
        }

#pragma unroll
        for (int f = 0; f < 8; ++f) {
#pragma unroll
            for (int r = 0; r < 4; ++r) {
                float val = acc[f][r] + bv[f];
                C[(rowBase + tile * 64 + 16 * w + lk * 4 + r) * HDIM + 16 * f + lr] = f2b(val);
                if (STATS) { psum[f] += val; psq[f] += val * val; }
            }
        }
    }

    if (STATS) {
        // reduce across the 4 lk-groups of the wave (same columns)
#pragma unroll
        for (int f = 0; f < 8; ++f) {
            psum[f] += __shfl_xor(psum[f], 16, 64);
            psum[f] += __shfl_xor(psum[f], 32, 64);
            psq[f]  += __shfl_xor(psq[f], 16, 64);
            psq[f]  += __shfl_xor(psq[f], 32, 64);
        }
        if (lk == 0) {
#pragma unroll
            for (int f = 0; f < 8; ++f) {
                red[w * 258 + 16 * f + lr]       = psum[f];
                red[w * 258 + 128 + 16 * f + lr] = psq[f];
            }
        }
        __syncthreads();
        if (t < 256) {
            float s = red[t] + red[258 + t] + red[2 * 258 + t] + red[3 * 258 + t];
            atomicAdd(&stOut[t], s);
        }
    }
}

// ---------------- CSR build (graph static per call) -------------------------
__global__ void deg_kernel(const int* __restrict__ dst, int* __restrict__ deg)
{
    int e = blockIdx.x * 256 + threadIdx.x;
    if (e < NEDGES) atomicAdd(&deg[dst[e]], 1);
}

__global__ __launch_bounds__(256) void scan1(const int* __restrict__ deg,
                                             int* __restrict__ rowptr,
                                             int* __restrict__ bsum)
{
    __shared__ int lds[256];
    const int t = threadIdx.x;
    const long base = (long)blockIdx.x * SCANB + t * 8;
    int v[8];
    int s = 0;
#pragma unroll
    for (int j = 0; j < 8; ++j) {
        long idx = base + j;
        v[j] = (idx < NNODES) ? deg[idx] : 0;
        s += v[j];
    }
    lds[t] = s;
    __syncthreads();
    for (int d = 1; d < 256; d <<= 1) {
        int x = (t >= d) ? lds[t - d] : 0;
        __syncthreads();
        lds[t] += x;
        __syncthreads();
    }
    int off = lds[t] - s;
    if (t == 255) bsum[blockIdx.x] = lds[255];
#pragma unroll
    for (int j = 0; j < 8; ++j) {
        long idx = base + j;
        if (idx < NNODES) rowptr[idx] = off;
        off += v[j];
    }
}

__global__ void scan2(int* __restrict__ bsum)
{
    __shared__ int lds[128];
    const int t = threadIdx.x;
    int v = (t < NSCANB) ? bsum[t] : 0;
    lds[t] = v;
    __syncthreads();
    for (int d = 1; d < 128; d <<= 1) {
        int x = (t >= d) ? lds[t - d] : 0;
        __syncthreads();
        lds[t] += x;
        __syncthreads();
    }
    if (t < NSCANB) bsum[t] = lds[t] - v;
}

__global__ void scan3(int* __restrict__ rowptr, const int* __restrict__ bsum,
                      int* __restrict__ cursor)
{
    long i = (long)blockIdx.x * 256 + threadIdx.x;
    if (i < NNODES) {
        int r = rowptr[i] + bsum[i / SCANB];
        rowptr[i] = r;
        cursor[i] = r;
    }
    if (i == 0) rowptr[NNODES] = NEDGES;
}

__global__ void fill_eidx(const int* __restrict__ src, const int* __restrict__ dst,
                          int* __restrict__ cursor, int* __restrict__ eidx)
{
    int e = blockIdx.x * 256 + threadIdx.x;
    if (e < NEDGES) {
        int pos = atomicAdd(&cursor[dst[e]], 1);
        eidx[pos] = src[e];
    }
}

// ---------------------------------------------------------------------------
// agg_fused: h[r] = FIRST ? HIN[r] : relu(bn3(Y[r])) + HIN[r]   (on the fly)
//            P[n] = (1+eps)*h[n] + sum_{m in N(n)} h[m]
// ---------------------------------------------------------------------------
template <bool FIRST>
__global__ __launch_bounds__(256) void agg_fused(
    const unsigned short* __restrict__ Y, const unsigned short* __restrict__ HIN,
    const float* __restrict__ st3, const float* __restrict__ g3,
    const float* __restrict__ b3, const int* __restrict__ rowptr,
    const int* __restrict__ eidx, const float* __restrict__ eps_gin, int layer,
    unsigned short* __restrict__ P)
{
    __shared__ float scb[128], shb[128];
    const int t = threadIdx.x;
    if (!FIRST) {
        if (t < 128) {
            float m = st3[t] * INV_N;
            float v = st3[128 + t] * INV_N - m * m;
            float s = g3[t] * rsqrtf(v + 1e-5f);
            scb[t] = s; shb[t] = b3[t] - m * s;
        }
        __syncthreads();
    }
    const int l16 = t & 15;
    const long n = (long)blockIdx.x * 16 + (t >> 4);
    const int c8 = l16 * 8;
    float sc[8], sh[8];
    if (!FIRST) {
#pragma unroll
        for (int j = 0; j < 8; ++j) { sc[j] = scb[c8 + j]; sh[j] = shb[c8 + j]; }
    }
    const float s = 1.0f + eps_gin[layer];
    float acc[8];
    {
        bf16x8 hv = *(const bf16x8*)&HIN[n * HDIM + c8];
        if (FIRST) {
#pragma unroll
            for (int j = 0; j < 8; ++j) acc[j] = s * b2f((unsigned short)hv[j]);
        } else {
            bf16x8 yv = *(const bf16x8*)&Y[n * HDIM + c8];
#pragma unroll
            for (int j = 0; j < 8; ++j)
                acc[j] = s * (relu_f(fmaf(b2f((unsigned short)yv[j]), sc[j], sh[j]))
                              + b2f((unsigned short)hv[j]));
        }
    }
    const int bg = rowptr[n], en = rowptr[n + 1];
    for (int i = bg; i < en; ++i) {
        long m = eidx[i];
        bf16x8 hv = *(const bf16x8*)&HIN[m * HDIM + c8];
        if (FIRST) {
#pragma unroll
            for (int j = 0; j < 8; ++j) acc[j] += b2f((unsigned short)hv[j]);
        } else {
            bf16x8 yv = *(const bf16x8*)&Y[m * HDIM + c8];
#pragma unroll
            for (int j = 0; j < 8; ++j)
                acc[j] += relu_f(fmaf(b2f((unsigned short)yv[j]), sc[j], sh[j]))
                          + b2f((unsigned short)hv[j]);
        }
    }
    bf16x8 o;
#pragma unroll
    for (int j = 0; j < 8; ++j) o[j] = (short)f2b(acc[j]);
    *(bf16x8*)&P[n * HDIM + c8] = o;
}

// ---------------------------------------------------------------------------
// x3: P = relu(bn2(P)) * snorm (in place), stats of result (pre-round f32).
// Grid-stride over 64-row tiles, register-accumulated stats, ONE reduction
// per block (512 blocks -> 131K atomics vs 800K before: atomic-bound fix).
// ---------------------------------------------------------------------------
__global__ __launch_bounds__(256) void x3_kernel(
    unsigned short* __restrict__ P, const float* __restrict__ st2,
    const float* __restrict__ g2, const float* __restrict__ b2v,
    const float* __restrict__ snorm, float* __restrict__ st3)
{
    __shared__ float scb[128], shb[128];
    __shared__ float red[16 * 132];
    const int t = threadIdx.x;
    if (t < 128) {
        float m = st2[t] * INV_N;
        float v = st2[128 + t] * INV_N - m * m;
        float s = g2[t] * rsqrtf(v + 1e-5f);
        scb[t] = s; shb[t] = b2v[t] - m * s;
    }
    __syncthreads();
    const int l16 = t & 15, g = t >> 4;
    const int c8 = l16 * 8;
    float sc[8], sh[8];
#pragma unroll
    for (int j = 0; j < 8; ++j) { sc[j] = scb[c8 + j]; sh[j] = shb[c8 + j]; }
    float sum[8] = {0, 0, 0, 0, 0, 0, 0, 0}, sq[8] = {0, 0, 0, 0, 0, 0, 0, 0};

    for (int tile = blockIdx.x; tile < NTILES; tile += X3GRID) {
        const long row0 = (long)tile * 64 + g * 4;
#pragma unroll
        for (int rr = 0; rr < 4; ++rr) {
            long row = row0 + rr;
            float sn = snorm[row];
            bf16x8 v = *(const bf16x8*)&P[row * HDIM + c8];
            bf16x8 o;
#pragma unroll
            for (int j = 0; j < 8; ++j) {
                float x = b2f((unsigned short)v[j]);
                x = relu_f(fmaf(x, sc[j], sh[j])) * sn;
                o[j] = (short)f2b(x);
                sum[j] += x; sq[j] += x * x;
            }
            *(bf16x8*)&P[row * HDIM + c8] = o;
        }
    }

#pragma unroll
    for (int j = 0; j < 8; ++j) red[g * 132 + c8 + j] = sum[j];
    __syncthreads();
    if (t < 128) {
        float s = 0;
#pragma unroll
        for (int gg = 0; gg < 16; ++gg) s += red[gg * 132 + t];
        atomicAdd(&st3[t], s);
    }
    __syncthreads();
#pragma unroll
    for (int j = 0; j < 8; ++j) red[g * 132 + c8 + j] = sq[j];
    __syncthreads();
    if (t < 128) {
        float s = 0;
#pragma unroll
        for (int gg = 0; gg < 16; ++gg) s += red[gg * 132 + t];
        atomicAdd(&st3[128 + t], s);
    }
}

// last layer: d[n] = (relu(bn3(Y[n])) + HIN[n]) . v ; gsum[gid[n]] += d[n]
__global__ __launch_bounds__(256) void fin_last(
    const unsigned short* __restrict__ Y, const unsigned short* __restrict__ HIN,
    const float* __restrict__ st3, const float* __restrict__ g3,
    const float* __restrict__ b3, const float* __restrict__ vvec,
    const int* __restrict__ gid, float* __restrict__ gsum)
{
    __shared__ float scb[128], shb[128];
    const int t = threadIdx.x;
    if (t < 128) {
        float m = st3[t] * INV_N;
        float va = st3[128 + t] * INV_N - m * m;
        float s = g3[t] * rsqrtf(va + 1e-5f);
        scb[t] = s; shb[t] = b3[t] - m * s;
    }
    __syncthreads();
    const int l16 = t & 15;
    const long n = (long)blockIdx.x * 16 + (t >> 4);
    const int c8 = l16 * 8;
    bf16x8 yv = *(const bf16x8*)&Y[n * HDIM + c8];
    bf16x8 hv = *(const bf16x8*)&HIN[n * HDIM + c8];
    float d = 0;
#pragma unroll
    for (int j = 0; j < 8; ++j) {
        float h = relu_f(fmaf(b2f((unsigned short)yv[j]), scb[c8 + j], shb[c8 + j]))
                  + b2f((unsigned short)hv[j]);
        d += h * vvec[c8 + j];
    }
#pragma unroll
    for (int off = 8; off > 0; off >>= 1) d += __shfl_down(d, off, 16);
    if (l16 == 0) atomicAdd(&gsum[gid[n]], d);
}

__global__ void gcnt_kernel(const int* __restrict__ gid, float* __restrict__ gcnt)
{
    int n = blockIdx.x * 256 + threadIdx.x;
    if (n < NNODES) atomicAdd(&gcnt[gid[n]], 1.0f);
}

__global__ void v_kernel(const float* __restrict__ W_ro, const float* __restrict__ W_pred,
                         float* __restrict__ v)
{
    int t = threadIdx.x;
    if (t < HDIM) {
        float s = 0;
        for (int j = 0; j < HDIM; ++j) s += W_ro[t * HDIM + j] * W_pred[j];
        v[t] = s;
    }
}

__global__ void score_kernel(const float* __restrict__ gsum, const float* __restrict__ gcnt,
                             const float* __restrict__ b_pred, float* __restrict__ out)
{
    int g = blockIdx.x * 256 + threadIdx.x;
    if (g < NGRAPH) out[g] = gsum[g] / fmaxf(gcnt[g], 1.0f) + b_pred[0];
}

extern "C" void kernel_launch(void* const* d_in, const int* in_sizes, int n_in,
                              void* d_out, int out_size, void* d_ws, size_t ws_size,
                              hipStream_t stream)
{
    const float* h_raw   = (const float*)d_in[0];
    const int*   src     = (const int*)d_in[1];
    const int*   dst     = (const int*)d_in[2];
    const int*   gid     = (const int*)d_in[3];
    const float* snorm   = (const float*)d_in[4];
    const float* W_emb   = (const float*)d_in[5];
    const float* eps_gin = (const float*)d_in[6];
    const float* W1      = (const float*)d_in[7];
    const float* b1      = (const float*)d_in[8];
    const float* bn1_g   = (const float*)d_in[9];
    const float* bn1_b   = (const float*)d_in[10];
    const float* W2      = (const float*)d_in[11];
    const float* b2      = (const float*)d_in[12];
    const float* bn2_g   = (const float*)d_in[13];
    const float* bn2_b   = (const float*)d_in[14];
    const float* bn3_g   = (const float*)d_in[15];
    const float* bn3_b   = (const float*)d_in[16];
    const float* W_ro    = (const float*)d_in[17];
    const float* W_pred  = (const float*)d_in[18];
    const float* b_pred  = (const float*)d_in[19];
    float* out = (float*)d_out;

    const size_t NH = (size_t)NNODES * HDIM;      // elements per [N,128]
    unsigned short* HIN = (unsigned short*)d_ws;
    unsigned short* Pa  = HIN + NH;
    unsigned short* Pb  = Pa + NH;
    float* Z      = (float*)(Pb + NH);
    float* statsb = Z;                  // 12 * 256
    float* gsum   = Z + 12 * 256;       // 8000
    float* gcnt   = gsum + NGRAPH;      // 8000
    float* vvec   = gcnt + NGRAPH;      // 128
    int* rowptr = (int*)(vvec + 128);          // N+1
    int* deg    = rowptr + NNODES + 1;         // N (becomes Wtb after scan1)
    int* cursor = deg + NNODES;                // N
    int* bsum   = cursor + NNODES;             // 128
    int* eidx   = bsum + 128;                  // E
    unsigned short* Wtb =
        (unsigned short*)(((uintptr_t)deg + 15) & ~(uintptr_t)15);  // 9*16384 u16

    hipMemsetAsync(Z, 0, 19072 * sizeof(float), stream);
    hipMemsetAsync(deg, 0, NNODES * sizeof(int), stream);

    gcnt_kernel<<<(NNODES + 255) / 256, 256, 0, stream>>>(gid, gcnt);
    v_kernel<<<1, 128, 0, stream>>>(W_ro, W_pred, vvec);

    // CSR build (deg consumed by scan1, then its space becomes Wtb)
    deg_kernel<<<(NEDGES + 255) / 256, 256, 0, stream>>>(dst, deg);
    scan1<<<NSCANB, 256, 0, stream>>>(deg, rowptr, bsum);
    scan2<<<1, 128, 0, stream>>>(bsum);
    scan3<<<(NNODES + 255) / 256, 256, 0, stream>>>(rowptr, bsum, cursor);
    fill_eidx<<<(NEDGES + 255) / 256, 256, 0, stream>>>(src, dst, cursor, eidx);

    // weights -> bf16 fragment-order [9][8][4][64][8]
    wconv<<<(9 * 16384) / 256, 256, 0, stream>>>(W_emb, W1, W2, Wtb);

    // embedding: HIN = bf16(h_raw @ W_emb)
    gemm_mfma<true, false, false><<<GGRID, 256, 0, stream>>>(
        h_raw, Wtb, nullptr, nullptr, nullptr, nullptr, HIN, nullptr);

    unsigned short* bufs[2] = {Pa, Pb};
    int cur = 0;
    for (int i = 0; i < NLAYER; ++i) {
        float* st1 = statsb + (i * 3 + 0) * 256;
        float* st2 = statsb + (i * 3 + 1) * 256;
        float* st3 = statsb + (i * 3 + 2) * 256;

        if (i == 0) {
            agg_fused<true><<<NNODES / 16, 256, 0, stream>>>(
                nullptr, HIN, nullptr, nullptr, nullptr,
                rowptr, eidx, eps_gin, 0, bufs[0]);
            cur = 0;
        } else {
            int nxt = cur ^ 1;
            float* st3p = statsb + ((i - 1) * 3 + 2) * 256;
            agg_fused<false><<<NNODES / 16, 256, 0, stream>>>(
                bufs[cur], HIN, st3p, bn3_g + (i - 1) * HDIM, bn3_b + (i - 1) * HDIM,
                rowptr, eidx, eps_gin, i, bufs[nxt]);
            cur = nxt;
        }
        unsigned short* B = bufs[cur];

        gemm_mfma<false, false, true><<<GGRID, 256, 0, stream>>>(
            B, Wtb + (size_t)(1 + i) * 16384, b1 + i * HDIM,
            nullptr, nullptr, nullptr, B, st1);
        gemm_mfma<false, true, true><<<GGRID, 256, 0, stream>>>(
            B, Wtb + (size_t)(5 + i) * 16384, b2 + i * HDIM,
            st1, bn1_g + i * HDIM, bn1_b + i * HDIM, B, st2);
        x3_kernel<<<X3GRID, 256, 0, stream>>>(
            B, st2, bn2_g + i * HDIM, bn2_b + i * HDIM, snorm, st3);
    }

    fin_last<<<NNODES / 16, 256, 0, stream>>>(
        bufs[cur], HIN, statsb + (3 * 3 + 2) * 256,
        bn3_g + 3 * HDIM, bn3_b + 3 * HDIM, vvec, gid, gsum);
    score_kernel<<<(NGRAPH + 255) / 256, 256, 0, stream>>>(gsum, gcnt, b_pred, out);
}

// Round 10
// 918.984 us; speedup vs baseline: 5.5229x; 1.0624x over previous
//
#include <hip/hip_runtime.h>

#define NNODES 200000
#define NEDGES 400000
#define NGRAPH 8000
#define ADIM 100
#define HDIM 128
#define NLAYER 4
#define SCANB 2048
#define NSCANB ((NNODES + SCANB - 1) / SCANB)   // 98
#define INV_N (1.0f / (float)NNODES)
#define GTILES 5                                 // row-tiles (64) per gemm block
#define GROWS (64 * GTILES)                      // 320 rows per block
#define GGRID (NNODES / GROWS)                   // 625 blocks
#define NTILES (NNODES / 64)                     // 3125
#define X3GRID 512
#define TPITCH 136                               // u16 pitch of transpose tile (272B, 16B-aligned)

typedef float4 f4;
typedef __attribute__((ext_vector_type(8))) short bf16x8;
typedef __attribute__((ext_vector_type(4))) float f32x4;

__device__ __forceinline__ float relu_f(float x) { return fmaxf(x, 0.0f); }

// f32 -> bf16 (RNE)
__device__ __forceinline__ unsigned short f2b(float x)
{
    unsigned int u = __float_as_uint(x);
    u = (u + 0x7FFFu + ((u >> 16) & 1u)) >> 16;
    return (unsigned short)u;
}
__device__ __forceinline__ float b2f(unsigned short b)
{
    return __uint_as_float(((unsigned int)b) << 16);
}

// ---------------------------------------------------------------------------
// Weight convert into MFMA B-fragment order:
// Wtb[m][f][ks][l][j] = bf16(W_m[k][n]), n = 16f + (l&15), k = 32ks + 8(l>>4) + j
// ---------------------------------------------------------------------------
__global__ void wconv(const float* __restrict__ W_emb, const float* __restrict__ W1,
                      const float* __restrict__ W2, unsigned short* __restrict__ Wtb)
{
    int id = blockIdx.x * 256 + threadIdx.x;   // 9*16384 total
    int m = id >> 14;
    int r = id & 16383;
    int j  = r & 7;
    int l  = (r >> 3) & 63;
    int ks = (r >> 9) & 3;
    int f  = r >> 11;
    int n = 16 * f + (l & 15);
    int k = 32 * ks + 8 * (l >> 4) + j;
    float v;
    if (m == 0)      v = (k < ADIM) ? W_emb[k * HDIM + n] : 0.0f;
    else if (m <= 4) v = W1[(size_t)(m - 1) * HDIM * HDIM + k * HDIM + n];
    else             v = W2[(size_t)(m - 5) * HDIM * HDIM + k * HDIM + n];
    Wtb[id] = f2b(v);
}

// ---------------------------------------------------------------------------
// MFMA GEMM: C[N,128] = f(A) @ W (+bias), optional col stats.
// Block = GTILES x (64 rows), 4 waves x 16 rows per tile. W staged once.
// Epilogue: per-wave LDS transpose -> fully coalesced 16B/lane C stores.
// (Round-9 bug fixed: readback now covers all 16 column-chunks — 4 iters,
//  sl = l&15, row = (l>>4)+4p; previous version stored only cols 0..63.)
// Stats in registers across tiles; one reduction per block. In-place safe.
// ---------------------------------------------------------------------------
template <bool EMB, bool APPLY, bool STATS>
__global__ __launch_bounds__(256, 3) void gemm_mfma(
    const void* __restrict__ Av, const unsigned short* __restrict__ Wt,
    const float* __restrict__ bias, const float* __restrict__ stIn,
    const float* __restrict__ gIn, const float* __restrict__ bIn,
    unsigned short* __restrict__ C, float* __restrict__ stOut)
{
    __shared__ unsigned short Wl[16384];          // 32 KB
    __shared__ unsigned short Tw[4 * 16 * TPITCH]; // 17 KB transpose tiles (per-wave)
    __shared__ float scb[APPLY ? 128 : 1];
    __shared__ float shb[APPLY ? 128 : 1];
    float* red = (float*)Tw;                      // aliased; used after final barrier

    const int t = threadIdx.x;

    if (APPLY && t < 128) {
        float m = stIn[t] * INV_N;
        float v = stIn[128 + t] * INV_N - m * m;
        float s = gIn[t] * rsqrtf(v + 1e-5f);
        scb[t] = s; shb[t] = bIn[t] - m * s;
    }
    // stage W (32 KB) once, coalesced, conflict-free
    for (int idx = t; idx < 2048; idx += 256)
        *(bf16x8*)&Wl[idx * 8] = *(const bf16x8*)&Wt[idx * 8];
    __syncthreads();

    const int w = t >> 6, l = t & 63;
    const int lr = l & 15, lk = l >> 4;
    const long rowBase = (long)blockIdx.x * GROWS;
    unsigned short* myT = &Tw[w * 16 * TPITCH];

    float psum[8], psq[8];
#pragma unroll
    for (int f = 0; f < 8; ++f) { psum[f] = 0.f; psq[f] = 0.f; }
    float bv[8];
#pragma unroll
    for (int f = 0; f < 8; ++f) bv[f] = STATS ? bias[16 * f + lr] : 0.0f;

#pragma unroll
    for (int tile = 0; tile < GTILES; ++tile) {
        const long rowt0 = rowBase + tile * 64 + 16 * w;
        const long arow = rowt0 + lr;

        bf16x8 af[4];
        if (EMB) {
            const float* A = (const float*)Av;
#pragma unroll
            for (int ks = 0; ks < 4; ++ks) {
                int k0 = ks * 32 + lk * 8;
                f4 a0 = {0, 0, 0, 0}, a1 = {0, 0, 0, 0};
                if (k0 < ADIM)      a0 = *(const f4*)&A[arow * ADIM + k0];
                if (k0 + 8 <= ADIM) a1 = *(const f4*)&A[arow * ADIM + k0 + 4];
                bf16x8 v;
                v[0] = (short)f2b(a0.x); v[1] = (short)f2b(a0.y);
                v[2] = (short)f2b(a0.z); v[3] = (short)f2b(a0.w);
                v[4] = (short)f2b(a1.x); v[5] = (short)f2b(a1.y);
                v[6] = (short)f2b(a1.z); v[7] = (short)f2b(a1.w);
                af[ks] = v;
            }
        } else {
            const unsigned short* A = (const unsigned short*)Av;
#pragma unroll
            for (int ks = 0; ks < 4; ++ks)
                af[ks] = *(const bf16x8*)&A[arow * HDIM + ks * 32 + lk * 8];
            if (APPLY) {
#pragma unroll
                for (int ks = 0; ks < 4; ++ks) {
                    int k0 = ks * 32 + lk * 8;
                    bf16x8 v = af[ks];
#pragma unroll
                    for (int j = 0; j < 8; ++j) {
                        float x = b2f((unsigned short)v[j]);
                        x = relu_f(fmaf(x, scb[k0 + j], shb[k0 + j]));
                        v[j] = (short)f2b(x);
                    }
                    af[ks] = v;
                }
            }
        }

        f32x4 acc[8];
#pragma unroll
        for (int f = 0; f < 8; ++f) acc[f] = (f32x4){0.f, 0.f, 0.f, 0.f};
#pragma unroll
        for (int ks = 0; ks < 4; ++ks) {
#pragma unroll
            for (int f = 0; f < 8; ++f) {
                bf16x8 bfr = *(const bf16x8*)&Wl[(f * 4 + ks) * 512 + l * 8];
                acc[f] = __builtin_amdgcn_mfma_f32_16x16x32_bf16(af[ks], bfr, acc[f], 0, 0, 0);
            }
        }

        // scatter D fragments (2B) into this wave's private LDS tile
#pragma unroll
        for (int f = 0; f < 8; ++f) {
#pragma unroll
            for (int r = 0; r < 4; ++r) {
                float val = acc[f][r] + bv[f];
                myT[(lk * 4 + r) * TPITCH + 16 * f + lr] = f2b(val);
                if (STATS) { psum[f] += val; psq[f] += val * val; }
            }
        }
        // read back row-major, fully coalesced global store (16B/lane).
        // 4 iters x 64 lanes x 16B = full 16x128 bf16 tile.
#pragma unroll
        for (int p = 0; p < 4; ++p) {
            int row = (l >> 4) + 4 * p;
            int sl = l & 15;
            bf16x8 v = *(const bf16x8*)&myT[row * TPITCH + sl * 8];
            *(bf16x8*)&C[(rowt0 + row) * HDIM + sl * 8] = v;
        }
    }

    if (STATS) {
        // reduce across the 4 lk-groups of the wave (same columns)
#pragma unroll
        for (int f = 0; f < 8; ++f) {
            psum[f] += __shfl_xor(psum[f], 16, 64);
            psum[f] += __shfl_xor(psum[f], 32, 64);
            psq[f]  += __shfl_xor(psq[f], 16, 64);
            psq[f]  += __shfl_xor(psq[f], 32, 64);
        }
        __syncthreads();   // all waves done with Tw -> safe to reuse as red
        if (lk == 0) {
#pragma unroll
            for (int f = 0; f < 8; ++f) {
                red[w * 258 + 16 * f + lr]       = psum[f];
                red[w * 258 + 128 + 16 * f + lr] = psq[f];
            }
        }
        __syncthreads();
        if (t < 256) {
            float s = red[t] + red[258 + t] + red[2 * 258 + t] + red[3 * 258 + t];
            atomicAdd(&stOut[t], s);
        }
    }
}

// ---------------- CSR build (graph static per call) -------------------------
__global__ void deg_kernel(const int* __restrict__ dst, int* __restrict__ deg)
{
    int e = blockIdx.x * 256 + threadIdx.x;
    if (e < NEDGES) atomicAdd(&deg[dst[e]], 1);
}

__global__ __launch_bounds__(256) void scan1(const int* __restrict__ deg,
                                             int* __restrict__ rowptr,
                                             int* __restrict__ bsum)
{
    __shared__ int lds[256];
    const int t = threadIdx.x;
    const long base = (long)blockIdx.x * SCANB + t * 8;
    int v[8];
    int s = 0;
#pragma unroll
    for (int j = 0; j < 8; ++j) {
        long idx = base + j;
        v[j] = (idx < NNODES) ? deg[idx] : 0;
        s += v[j];
    }
    lds[t] = s;
    __syncthreads();
    for (int d = 1; d < 256; d <<= 1) {
        int x = (t >= d) ? lds[t - d] : 0;
        __syncthreads();
        lds[t] += x;
        __syncthreads();
    }
    int off = lds[t] - s;
    if (t == 255) bsum[blockIdx.x] = lds[255];
#pragma unroll
    for (int j = 0; j < 8; ++j) {
        long idx = base + j;
        if (idx < NNODES) rowptr[idx] = off;
        off += v[j];
    }
}

__global__ void scan2(int* __restrict__ bsum)
{
    __shared__ int lds[128];
    const int t = threadIdx.x;
    int v = (t < NSCANB) ? bsum[t] : 0;
    lds[t] = v;
    __syncthreads();
    for (int d = 1; d < 128; d <<= 1) {
        int x = (t >= d) ? lds[t - d] : 0;
        __syncthreads();
        lds[t] += x;
        __syncthreads();
    }
    if (t < NSCANB) bsum[t] = lds[t] - v;
}

__global__ void scan3(int* __restrict__ rowptr, const int* __restrict__ bsum,
                      int* __restrict__ cursor)
{
    long i = (long)blockIdx.x * 256 + threadIdx.x;
    if (i < NNODES) {
        int r = rowptr[i] + bsum[i / SCANB];
        rowptr[i] = r;
        cursor[i] = r;
    }
    if (i == 0) rowptr[NNODES] = NEDGES;
}

__global__ void fill_eidx(const int* __restrict__ src, const int* __restrict__ dst,
                          int* __restrict__ cursor, int* __restrict__ eidx)
{
    int e = blockIdx.x * 256 + threadIdx.x;
    if (e < NEDGES) {
        int pos = atomicAdd(&cursor[dst[e]], 1);
        eidx[pos] = src[e];
    }
}

// ---------------------------------------------------------------------------
// agg_fused: h[r] = FIRST ? HIN[r] : relu(bn3(Y[r])) + HIN[r]   (on the fly)
//            P[n] = (1+eps)*h[n] + sum_{m in N(n)} h[m]
// ---------------------------------------------------------------------------
template <bool FIRST>
__global__ __launch_bounds__(256) void agg_fused(
    const unsigned short* __restrict__ Y, const unsigned short* __restrict__ HIN,
    const float* __restrict__ st3, const float* __restrict__ g3,
    const float* __restrict__ b3, const int* __restrict__ rowptr,
    const int* __restrict__ eidx, const float* __restrict__ eps_gin, int layer,
    unsigned short* __restrict__ P)
{
    __shared__ float scb[128], shb[128];
    const int t = threadIdx.x;
    if (!FIRST) {
        if (t < 128) {
            float m = st3[t] * INV_N;
            float v = st3[128 + t] * INV_N - m * m;
            float s = g3[t] * rsqrtf(v + 1e-5f);
            scb[t] = s; shb[t] = b3[t] - m * s;
        }
        __syncthreads();
    }
    const int l16 = t & 15;
    const long n = (long)blockIdx.x * 16 + (t >> 4);
    const int c8 = l16 * 8;
    float sc[8], sh[8];
    if (!FIRST) {
#pragma unroll
        for (int j = 0; j < 8; ++j) { sc[j] = scb[c8 + j]; sh[j] = shb[c8 + j]; }
    }
    const float s = 1.0f + eps_gin[layer];
    float acc[8];
    {
        bf16x8 hv = *(const bf16x8*)&HIN[n * HDIM + c8];
        if (FIRST) {
#pragma unroll
            for (int j = 0; j < 8; ++j) acc[j] = s * b2f((unsigned short)hv[j]);
        } else {
            bf16x8 yv = *(const bf16x8*)&Y[n * HDIM + c8];
#pragma unroll
            for (int j = 0; j < 8; ++j)
                acc[j] = s * (relu_f(fmaf(b2f((unsigned short)yv[j]), sc[j], sh[j]))
                              + b2f((unsigned short)hv[j]));
        }
    }
    const int bg = rowptr[n], en = rowptr[n + 1];
    for (int i = bg; i < en; ++i) {
        long m = eidx[i];
        bf16x8 hv = *(const bf16x8*)&HIN[m * HDIM + c8];
        if (FIRST) {
#pragma unroll
            for (int j = 0; j < 8; ++j) acc[j] += b2f((unsigned short)hv[j]);
        } else {
            bf16x8 yv = *(const bf16x8*)&Y[m * HDIM + c8];
#pragma unroll
            for (int j = 0; j < 8; ++j)
                acc[j] += relu_f(fmaf(b2f((unsigned short)yv[j]), sc[j], sh[j]))
                          + b2f((unsigned short)hv[j]);
        }
    }
    bf16x8 o;
#pragma unroll
    for (int j = 0; j < 8; ++j) o[j] = (short)f2b(acc[j]);
    *(bf16x8*)&P[n * HDIM + c8] = o;
}

// ---------------------------------------------------------------------------
// x3: P = relu(bn2(P)) * snorm (in place), stats of result (pre-round f32).
// Grid-stride, register stats, one reduction per block.
// ---------------------------------------------------------------------------
__global__ __launch_bounds__(256) void x3_kernel(
    unsigned short* __restrict__ P, const float* __restrict__ st2,
    const float* __restrict__ g2, const float* __restrict__ b2v,
    const float* __restrict__ snorm, float* __restrict__ st3)
{
    __shared__ float scb[128], shb[128];
    __shared__ float red[16 * 132];
    const int t = threadIdx.x;
    if (t < 128) {
        float m = st2[t] * INV_N;
        float v = st2[128 + t] * INV_N - m * m;
        float s = g2[t] * rsqrtf(v + 1e-5f);
        scb[t] = s; shb[t] = b2v[t] - m * s;
    }
    __syncthreads();
    const int l16 = t & 15, g = t >> 4;
    const int c8 = l16 * 8;
    float sc[8], sh[8];
#pragma unroll
    for (int j = 0; j < 8; ++j) { sc[j] = scb[c8 + j]; sh[j] = shb[c8 + j]; }
    float sum[8] = {0, 0, 0, 0, 0, 0, 0, 0}, sq[8] = {0, 0, 0, 0, 0, 0, 0, 0};

    for (int tile = blockIdx.x; tile < NTILES; tile += X3GRID) {
        const long row0 = (long)tile * 64 + g * 4;
#pragma unroll
        for (int rr = 0; rr < 4; ++rr) {
            long row = row0 + rr;
            float sn = snorm[row];
            bf16x8 v = *(const bf16x8*)&P[row * HDIM + c8];
            bf16x8 o;
#pragma unroll
            for (int j = 0; j < 8; ++j) {
                float x = b2f((unsigned short)v[j]);
                x = relu_f(fmaf(x, sc[j], sh[j])) * sn;
                o[j] = (short)f2b(x);
                sum[j] += x; sq[j] += x * x;
            }
            *(bf16x8*)&P[row * HDIM + c8] = o;
        }
    }

#pragma unroll
    for (int j = 0; j < 8; ++j) red[g * 132 + c8 + j] = sum[j];
    __syncthreads();
    if (t < 128) {
        float s = 0;
#pragma unroll
        for (int gg = 0; gg < 16; ++gg) s += red[gg * 132 + t];
        atomicAdd(&st3[t], s);
    }
    __syncthreads();
#pragma unroll
    for (int j = 0; j < 8; ++j) red[g * 132 + c8 + j] = sq[j];
    __syncthreads();
    if (t < 128) {
        float s = 0;
#pragma unroll
        for (int gg = 0; gg < 16; ++gg) s += red[gg * 132 + t];
        atomicAdd(&st3[128 + t], s);
    }
}

// last layer: d[n] = (relu(bn3(Y[n])) + HIN[n]) . v ; gsum[gid[n]] += d[n]
__global__ __launch_bounds__(256) void fin_last(
    const unsigned short* __restrict__ Y, const unsigned short* __restrict__ HIN,
    const float* __restrict__ st3, const float* __restrict__ g3,
    const float* __restrict__ b3, const float* __restrict__ vvec,
    const int* __restrict__ gid, float* __restrict__ gsum)
{
    __shared__ float scb[128], shb[128];
    const int t = threadIdx.x;
    if (t < 128) {
        float m = st3[t] * INV_N;
        float va = st3[128 + t] * INV_N - m * m;
        float s = g3[t] * rsqrtf(va + 1e-5f);
        scb[t] = s; shb[t] = b3[t] - m * s;
    }
    __syncthreads();
    const int l16 = t & 15;
    const long n = (long)blockIdx.x * 16 + (t >> 4);
    const int c8 = l16 * 8;
    bf16x8 yv = *(const bf16x8*)&Y[n * HDIM + c8];
    bf16x8 hv = *(const bf16x8*)&HIN[n * HDIM + c8];
    float d = 0;
#pragma unroll
    for (int j = 0; j < 8; ++j) {
        float h = relu_f(fmaf(b2f((unsigned short)yv[j]), scb[c8 + j], shb[c8 + j]))
                  + b2f((unsigned short)hv[j]);
        d += h * vvec[c8 + j];
    }
#pragma unroll
    for (int off = 8; off > 0; off >>= 1) d += __shfl_down(d, off, 16);
    if (l16 == 0) atomicAdd(&gsum[gid[n]], d);
}

__global__ void gcnt_kernel(const int* __restrict__ gid, float* __restrict__ gcnt)
{
    int n = blockIdx.x * 256 + threadIdx.x;
    if (n < NNODES) atomicAdd(&gcnt[gid[n]], 1.0f);
}

__global__ void v_kernel(const float* __restrict__ W_ro, const float* __restrict__ W_pred,
                         float* __restrict__ v)
{
    int t = threadIdx.x;
    if (t < HDIM) {
        float s = 0;
        for (int j = 0; j < HDIM; ++j) s += W_ro[t * HDIM + j] * W_pred[j];
        v[t] = s;
    }
}

__global__ void score_kernel(const float* __restrict__ gsum, const float* __restrict__ gcnt,
                             const float* __restrict__ b_pred, float* __restrict__ out)
{
    int g = blockIdx.x * 256 + threadIdx.x;
    if (g < NGRAPH) out[g] = gsum[g] / fmaxf(gcnt[g], 1.0f) + b_pred[0];
}

extern "C" void kernel_launch(void* const* d_in, const int* in_sizes, int n_in,
                              void* d_out, int out_size, void* d_ws, size_t ws_size,
                              hipStream_t stream)
{
    const float* h_raw   = (const float*)d_in[0];
    const int*   src     = (const int*)d_in[1];
    const int*   dst     = (const int*)d_in[2];
    const int*   gid     = (const int*)d_in[3];
    const float* snorm   = (const float*)d_in[4];
    const float* W_emb   = (const float*)d_in[5];
    const float* eps_gin = (const float*)d_in[6];
    const float* W1      = (const float*)d_in[7];
    const float* b1      = (const float*)d_in[8];
    const float* bn1_g   = (const float*)d_in[9];
    const float* bn1_b   = (const float*)d_in[10];
    const float* W2      = (const float*)d_in[11];
    const float* b2      = (const float*)d_in[12];
    const float* bn2_g   = (const float*)d_in[13];
    const float* bn2_b   = (const float*)d_in[14];
    const float* bn3_g   = (const float*)d_in[15];
    const float* bn3_b   = (const float*)d_in[16];
    const float* W_ro    = (const float*)d_in[17];
    const float* W_pred  = (const float*)d_in[18];
    const float* b_pred  = (const float*)d_in[19];
    float* out = (float*)d_out;

    const size_t NH = (size_t)NNODES * HDIM;      // elements per [N,128]
    unsigned short* HIN = (unsigned short*)d_ws;
    unsigned short* Pa  = HIN + NH;
    unsigned short* Pb  = Pa + NH;
    float* Z      = (float*)(Pb + NH);
    float* statsb = Z;                  // 12 * 256
    float* gsum   = Z + 12 * 256;       // 8000
    float* gcnt   = gsum + NGRAPH;      // 8000
    float* vvec   = gcnt + NGRAPH;      // 128
    int* rowptr = (int*)(vvec + 128);          // N+1
    int* deg    = rowptr + NNODES + 1;         // N (becomes Wtb after scan1)
    int* cursor = deg + NNODES;                // N
    int* bsum   = cursor + NNODES;             // 128
    int* eidx   = bsum + 128;                  // E
    unsigned short* Wtb =
        (unsigned short*)(((uintptr_t)deg + 15) & ~(uintptr_t)15);  // 9*16384 u16

    hipMemsetAsync(Z, 0, 19072 * sizeof(float), stream);
    hipMemsetAsync(deg, 0, NNODES * sizeof(int), stream);

    gcnt_kernel<<<(NNODES + 255) / 256, 256, 0, stream>>>(gid, gcnt);
    v_kernel<<<1, 128, 0, stream>>>(W_ro, W_pred, vvec);

    // CSR build (deg consumed by scan1, then its space becomes Wtb)
    deg_kernel<<<(NEDGES + 255) / 256, 256, 0, stream>>>(dst, deg);
    scan1<<<NSCANB, 256, 0, stream>>>(deg, rowptr, bsum);
    scan2<<<1, 128, 0, stream>>>(bsum);
    scan3<<<(NNODES + 255) / 256, 256, 0, stream>>>(rowptr, bsum, cursor);
    fill_eidx<<<(NEDGES + 255) / 256, 256, 0, stream>>>(src, dst, cursor, eidx);

    // weights -> bf16 fragment-order [9][8][4][64][8]
    wconv<<<(9 * 16384) / 256, 256, 0, stream>>>(W_emb, W1, W2, Wtb);

    // embedding: HIN = bf16(h_raw @ W_emb)
    gemm_mfma<true, false, false><<<GGRID, 256, 0, stream>>>(
        h_raw, Wtb, nullptr, nullptr, nullptr, nullptr, HIN, nullptr);

    unsigned short* bufs[2] = {Pa, Pb};
    int cur = 0;
    for (int i = 0; i < NLAYER; ++i) {
        float* st1 = statsb + (i * 3 + 0) * 256;
        float* st2 = statsb + (i * 3 + 1) * 256;
        float* st3 = statsb + (i * 3 + 2) * 256;

        if (i == 0) {
            agg_fused<true><<<NNODES / 16, 256, 0, stream>>>(
                nullptr, HIN, nullptr, nullptr, nullptr,
                rowptr, eidx, eps_gin, 0, bufs[0]);
            cur = 0;
        } else {
            int nxt = cur ^ 1;
            float* st3p = statsb + ((i - 1) * 3 + 2) * 256;
            agg_fused<false><<<NNODES / 16, 256, 0, stream>>>(
                bufs[cur], HIN, st3p, bn3_g + (i - 1) * HDIM, bn3_b + (i - 1) * HDIM,
                rowptr, eidx, eps_gin, i, bufs[nxt]);
            cur = nxt;
        }
        unsigned short* B = bufs[cur];

        gemm_mfma<false, false, true><<<GGRID, 256, 0, stream>>>(
            B, Wtb + (size_t)(1 + i) * 16384, b1 + i * HDIM,
            nullptr, nullptr, nullptr, B, st1);
        gemm_mfma<false, true, true><<<GGRID, 256, 0, stream>>>(
            B, Wtb + (size_t)(5 + i) * 16384, b2 + i * HDIM,
            st1, bn1_g + i * HDIM, bn1_b + i * HDIM, B, st2);
        x3_kernel<<<X3GRID, 256, 0, stream>>>(
            B, st2, bn2_g + i * HDIM, bn2_b + i * HDIM, snorm, st3);
    }

    fin_last<<<NNODES / 16, 256, 0, stream>>>(
        bufs[cur], HIN, statsb + (3 * 3 + 2) * 256,
        bn3_g + 3 * HDIM, bn3_b + 3 * HDIM, vvec, gid, gsum);
    score_kernel<<<(NGRAPH + 255) / 256, 256, 0, stream>>>(gsum, gcnt, b_pred, out);
}

// Round 11
// 915.393 us; speedup vs baseline: 5.5446x; 1.0039x over previous
//
#include <hip/hip_runtime.h>

#define NNODES 200000
#define NEDGES 400000
#define NGRAPH 8000
#define ADIM 100
#define HDIM 128
#define NLAYER 4
#define SCANB 2048
#define NSCANB ((NNODES + SCANB - 1) / SCANB)   // 98
#define INV_N (1.0f / (float)NNODES)
#define GTILES 5                                 // row-tiles (64) per gemm block
#define GROWS (64 * GTILES)                      // 320 rows per block
#define GGRID (NNODES / GROWS)                   // 625 blocks
#define NTILES (NNODES / 64)                     // 3125
#define X3GRID 512
#define TPITCH 136                               // u16 pitch of transpose tile

typedef float4 f4;
typedef __attribute__((ext_vector_type(8))) short bf16x8;
typedef __attribute__((ext_vector_type(4))) float f32x4;

__device__ __forceinline__ float relu_f(float x) { return fmaxf(x, 0.0f); }

// f32 -> bf16 (RNE)
__device__ __forceinline__ unsigned short f2b(float x)
{
    unsigned int u = __float_as_uint(x);
    u = (u + 0x7FFFu + ((u >> 16) & 1u)) >> 16;
    return (unsigned short)u;
}
__device__ __forceinline__ float b2f(unsigned short b)
{
    return __uint_as_float(((unsigned int)b) << 16);
}

// ---------------------------------------------------------------------------
// Weight convert into MFMA B-fragment order:
// Wtb[m][f][ks][l][j] = bf16(W_m[k][n]), n = 16f + (l&15), k = 32ks + 8(l>>4) + j
// ---------------------------------------------------------------------------
__global__ void wconv(const float* __restrict__ W_emb, const float* __restrict__ W1,
                      const float* __restrict__ W2, unsigned short* __restrict__ Wtb)
{
    int id = blockIdx.x * 256 + threadIdx.x;   // 9*16384 total
    int m = id >> 14;
    int r = id & 16383;
    int j  = r & 7;
    int l  = (r >> 3) & 63;
    int ks = (r >> 9) & 3;
    int f  = r >> 11;
    int n = 16 * f + (l & 15);
    int k = 32 * ks + 8 * (l >> 4) + j;
    float v;
    if (m == 0)      v = (k < ADIM) ? W_emb[k * HDIM + n] : 0.0f;
    else if (m <= 4) v = W1[(size_t)(m - 1) * HDIM * HDIM + k * HDIM + n];
    else             v = W2[(size_t)(m - 5) * HDIM * HDIM + k * HDIM + n];
    Wtb[id] = f2b(v);
}

// ---------------------------------------------------------------------------
// MFMA GEMM: C[N,128] = f(A) @ W (+bias), optional col stats.
// Block = GTILES x (64 rows), 4 waves x 16 rows per tile. W staged once.
// Epilogue: per-wave LDS transpose -> fully coalesced 16B/lane C stores.
// OUT-OF-PLACE (C != A): tests round-10 theory that in-place read+rewrite
// of the same lines caused the 2.15x HBM write amplification.
// ---------------------------------------------------------------------------
template <bool EMB, bool APPLY, bool STATS>
__global__ __launch_bounds__(256, 3) void gemm_mfma(
    const void* __restrict__ Av, const unsigned short* __restrict__ Wt,
    const float* __restrict__ bias, const float* __restrict__ stIn,
    const float* __restrict__ gIn, const float* __restrict__ bIn,
    unsigned short* __restrict__ C, float* __restrict__ stOut)
{
    __shared__ unsigned short Wl[16384];           // 32 KB
    __shared__ unsigned short Tw[4 * 16 * TPITCH]; // 17 KB transpose tiles
    __shared__ float scb[APPLY ? 128 : 1];
    __shared__ float shb[APPLY ? 128 : 1];
    float* red = (float*)Tw;                       // aliased after final barrier

    const int t = threadIdx.x;

    if (APPLY && t < 128) {
        float m = stIn[t] * INV_N;
        float v = stIn[128 + t] * INV_N - m * m;
        float s = gIn[t] * rsqrtf(v + 1e-5f);
        scb[t] = s; shb[t] = bIn[t] - m * s;
    }
    for (int idx = t; idx < 2048; idx += 256)
        *(bf16x8*)&Wl[idx * 8] = *(const bf16x8*)&Wt[idx * 8];
    __syncthreads();

    const int w = t >> 6, l = t & 63;
    const int lr = l & 15, lk = l >> 4;
    const long rowBase = (long)blockIdx.x * GROWS;
    unsigned short* myT = &Tw[w * 16 * TPITCH];

    float psum[8], psq[8];
#pragma unroll
    for (int f = 0; f < 8; ++f) { psum[f] = 0.f; psq[f] = 0.f; }
    float bv[8];
#pragma unroll
    for (int f = 0; f < 8; ++f) bv[f] = STATS ? bias[16 * f + lr] : 0.0f;

#pragma unroll
    for (int tile = 0; tile < GTILES; ++tile) {
        const long rowt0 = rowBase + tile * 64 + 16 * w;
        const long arow = rowt0 + lr;

        bf16x8 af[4];
        if (EMB) {
            const float* A = (const float*)Av;
#pragma unroll
            for (int ks = 0; ks < 4; ++ks) {
                int k0 = ks * 32 + lk * 8;
                f4 a0 = {0, 0, 0, 0}, a1 = {0, 0, 0, 0};
                if (k0 < ADIM)      a0 = *(const f4*)&A[arow * ADIM + k0];
                if (k0 + 8 <= ADIM) a1 = *(const f4*)&A[arow * ADIM + k0 + 4];
                bf16x8 v;
                v[0] = (short)f2b(a0.x); v[1] = (short)f2b(a0.y);
                v[2] = (short)f2b(a0.z); v[3] = (short)f2b(a0.w);
                v[4] = (short)f2b(a1.x); v[5] = (short)f2b(a1.y);
                v[6] = (short)f2b(a1.z); v[7] = (short)f2b(a1.w);
                af[ks] = v;
            }
        } else {
            const unsigned short* A = (const unsigned short*)Av;
#pragma unroll
            for (int ks = 0; ks < 4; ++ks)
                af[ks] = *(const bf16x8*)&A[arow * HDIM + ks * 32 + lk * 8];
            if (APPLY) {
#pragma unroll
                for (int ks = 0; ks < 4; ++ks) {
                    int k0 = ks * 32 + lk * 8;
                    bf16x8 v = af[ks];
#pragma unroll
                    for (int j = 0; j < 8; ++j) {
                        float x = b2f((unsigned short)v[j]);
                        x = relu_f(fmaf(x, scb[k0 + j], shb[k0 + j]));
                        v[j] = (short)f2b(x);
                    }
                    af[ks] = v;
                }
            }
        }

        f32x4 acc[8];
#pragma unroll
        for (int f = 0; f < 8; ++f) acc[f] = (f32x4){0.f, 0.f, 0.f, 0.f};
#pragma unroll
        for (int ks = 0; ks < 4; ++ks) {
#pragma unroll
            for (int f = 0; f < 8; ++f) {
                bf16x8 bfr = *(const bf16x8*)&Wl[(f * 4 + ks) * 512 + l * 8];
                acc[f] = __builtin_amdgcn_mfma_f32_16x16x32_bf16(af[ks], bfr, acc[f], 0, 0, 0);
            }
        }

        // scatter D fragments (2B) into this wave's private LDS tile
#pragma unroll
        for (int f = 0; f < 8; ++f) {
#pragma unroll
            for (int r = 0; r < 4; ++r) {
                float val = acc[f][r] + bv[f];
                myT[(lk * 4 + r) * TPITCH + 16 * f + lr] = f2b(val);
                if (STATS) { psum[f] += val; psq[f] += val * val; }
            }
        }
        // read back row-major, fully coalesced global store (16B/lane):
        // 4 iters x 64 lanes x 16B = full 16x128 tile.
#pragma unroll
        for (int p = 0; p < 4; ++p) {
            int row = (l >> 4) + 4 * p;
            int sl = l & 15;
            bf16x8 v = *(const bf16x8*)&myT[row * TPITCH + sl * 8];
            *(bf16x8*)&C[(rowt0 + row) * HDIM + sl * 8] = v;
        }
    }

    if (STATS) {
#pragma unroll
        for (int f = 0; f < 8; ++f) {
            psum[f] += __shfl_xor(psum[f], 16, 64);
            psum[f] += __shfl_xor(psum[f], 32, 64);
            psq[f]  += __shfl_xor(psq[f], 16, 64);
            psq[f]  += __shfl_xor(psq[f], 32, 64);
        }
        __syncthreads();   // all waves done with Tw -> reuse as red
        if (lk == 0) {
#pragma unroll
            for (int f = 0; f < 8; ++f) {
                red[w * 258 + 16 * f + lr]       = psum[f];
                red[w * 258 + 128 + 16 * f + lr] = psq[f];
            }
        }
        __syncthreads();
        if (t < 256) {
            float s = red[t] + red[258 + t] + red[2 * 258 + t] + red[3 * 258 + t];
            atomicAdd(&stOut[t], s);
        }
    }
}

// ---------------- CSR build (graph static per call) -------------------------
__global__ void deg_kernel(const int* __restrict__ dst, int* __restrict__ deg)
{
    int e = blockIdx.x * 256 + threadIdx.x;
    if (e < NEDGES) atomicAdd(&deg[dst[e]], 1);
}

__global__ __launch_bounds__(256) void scan1(const int* __restrict__ deg,
                                             int* __restrict__ rowptr,
                                             int* __restrict__ bsum)
{
    __shared__ int lds[256];
    const int t = threadIdx.x;
    const long base = (long)blockIdx.x * SCANB + t * 8;
    int v[8];
    int s = 0;
#pragma unroll
    for (int j = 0; j < 8; ++j) {
        long idx = base + j;
        v[j] = (idx < NNODES) ? deg[idx] : 0;
        s += v[j];
    }
    lds[t] = s;
    __syncthreads();
    for (int d = 1; d < 256; d <<= 1) {
        int x = (t >= d) ? lds[t - d] : 0;
        __syncthreads();
        lds[t] += x;
        __syncthreads();
    }
    int off = lds[t] - s;
    if (t == 255) bsum[blockIdx.x] = lds[255];
#pragma unroll
    for (int j = 0; j < 8; ++j) {
        long idx = base + j;
        if (idx < NNODES) rowptr[idx] = off;
        off += v[j];
    }
}

__global__ void scan2(int* __restrict__ bsum)
{
    __shared__ int lds[128];
    const int t = threadIdx.x;
    int v = (t < NSCANB) ? bsum[t] : 0;
    lds[t] = v;
    __syncthreads();
    for (int d = 1; d < 128; d <<= 1) {
        int x = (t >= d) ? lds[t - d] : 0;
        __syncthreads();
        lds[t] += x;
        __syncthreads();
    }
    if (t < NSCANB) bsum[t] = lds[t] - v;
}

__global__ void scan3(int* __restrict__ rowptr, const int* __restrict__ bsum,
                      int* __restrict__ cursor)
{
    long i = (long)blockIdx.x * 256 + threadIdx.x;
    if (i < NNODES) {
        int r = rowptr[i] + bsum[i / SCANB];
        rowptr[i] = r;
        cursor[i] = r;
    }
    if (i == 0) rowptr[NNODES] = NEDGES;
}

__global__ void fill_eidx(const int* __restrict__ src, const int* __restrict__ dst,
                          int* __restrict__ cursor, int* __restrict__ eidx)
{
    int e = blockIdx.x * 256 + threadIdx.x;
    if (e < NEDGES) {
        int pos = atomicAdd(&cursor[dst[e]], 1);
        eidx[pos] = src[e];
    }
}

// ---------------------------------------------------------------------------
// agg_fused: h[r] = FIRST ? HIN[r] : relu(bn3(Y[r])) + HIN[r]   (on the fly)
//            P[n] = (1+eps)*h[n] + sum_{m in N(n)} h[m]
// ---------------------------------------------------------------------------
template <bool FIRST>
__global__ __launch_bounds__(256) void agg_fused(
    const unsigned short* __restrict__ Y, const unsigned short* __restrict__ HIN,
    const float* __restrict__ st3, const float* __restrict__ g3,
    const float* __restrict__ b3, const int* __restrict__ rowptr,
    const int* __restrict__ eidx, const float* __restrict__ eps_gin, int layer,
    unsigned short* __restrict__ P)
{
    __shared__ float scb[128], shb[128];
    const int t = threadIdx.x;
    if (!FIRST) {
        if (t < 128) {
            float m = st3[t] * INV_N;
            float v = st3[128 + t] * INV_N - m * m;
            float s = g3[t] * rsqrtf(v + 1e-5f);
            scb[t] = s; shb[t] = b3[t] - m * s;
        }
        __syncthreads();
    }
    const int l16 = t & 15;
    const long n = (long)blockIdx.x * 16 + (t >> 4);
    const int c8 = l16 * 8;
    float sc[8], sh[8];
    if (!FIRST) {
#pragma unroll
        for (int j = 0; j < 8; ++j) { sc[j] = scb[c8 + j]; sh[j] = shb[c8 + j]; }
    }
    const float s = 1.0f + eps_gin[layer];
    float acc[8];
    {
        bf16x8 hv = *(const bf16x8*)&HIN[n * HDIM + c8];
        if (FIRST) {
#pragma unroll
            for (int j = 0; j < 8; ++j) acc[j] = s * b2f((unsigned short)hv[j]);
        } else {
            bf16x8 yv = *(const bf16x8*)&Y[n * HDIM + c8];
#pragma unroll
            for (int j = 0; j < 8; ++j)
                acc[j] = s * (relu_f(fmaf(b2f((unsigned short)yv[j]), sc[j], sh[j]))
                              + b2f((unsigned short)hv[j]));
        }
    }
    const int bg = rowptr[n], en = rowptr[n + 1];
    for (int i = bg; i < en; ++i) {
        long m = eidx[i];
        bf16x8 hv = *(const bf16x8*)&HIN[m * HDIM + c8];
        if (FIRST) {
#pragma unroll
            for (int j = 0; j < 8; ++j) acc[j] += b2f((unsigned short)hv[j]);
        } else {
            bf16x8 yv = *(const bf16x8*)&Y[m * HDIM + c8];
#pragma unroll
            for (int j = 0; j < 8; ++j)
                acc[j] += relu_f(fmaf(b2f((unsigned short)yv[j]), sc[j], sh[j]))
                          + b2f((unsigned short)hv[j]);
        }
    }
    bf16x8 o;
#pragma unroll
    for (int j = 0; j < 8; ++j) o[j] = (short)f2b(acc[j]);
    *(bf16x8*)&P[n * HDIM + c8] = o;
}

// ---------------------------------------------------------------------------
// x3: P = relu(bn2(P)) * snorm (in place), stats of result (pre-round f32).
// ---------------------------------------------------------------------------
__global__ __launch_bounds__(256) void x3_kernel(
    unsigned short* __restrict__ P, const float* __restrict__ st2,
    const float* __restrict__ g2, const float* __restrict__ b2v,
    const float* __restrict__ snorm, float* __restrict__ st3)
{
    __shared__ float scb[128], shb[128];
    __shared__ float red[16 * 132];
    const int t = threadIdx.x;
    if (t < 128) {
        float m = st2[t] * INV_N;
        float v = st2[128 + t] * INV_N - m * m;
        float s = g2[t] * rsqrtf(v + 1e-5f);
        scb[t] = s; shb[t] = b2v[t] - m * s;
    }
    __syncthreads();
    const int l16 = t & 15, g = t >> 4;
    const int c8 = l16 * 8;
    float sc[8], sh[8];
#pragma unroll
    for (int j = 0; j < 8; ++j) { sc[j] = scb[c8 + j]; sh[j] = shb[c8 + j]; }
    float sum[8] = {0, 0, 0, 0, 0, 0, 0, 0}, sq[8] = {0, 0, 0, 0, 0, 0, 0, 0};

    for (int tile = blockIdx.x; tile < NTILES; tile += X3GRID) {
        const long row0 = (long)tile * 64 + g * 4;
#pragma unroll
        for (int rr = 0; rr < 4; ++rr) {
            long row = row0 + rr;
            float sn = snorm[row];
            bf16x8 v = *(const bf16x8*)&P[row * HDIM + c8];
            bf16x8 o;
#pragma unroll
            for (int j = 0; j < 8; ++j) {
                float x = b2f((unsigned short)v[j]);
                x = relu_f(fmaf(x, sc[j], sh[j])) * sn;
                o[j] = (short)f2b(x);
                sum[j] += x; sq[j] += x * x;
            }
            *(bf16x8*)&P[row * HDIM + c8] = o;
        }
    }

#pragma unroll
    for (int j = 0; j < 8; ++j) red[g * 132 + c8 + j] = sum[j];
    __syncthreads();
    if (t < 128) {
        float s = 0;
#pragma unroll
        for (int gg = 0; gg < 16; ++gg) s += red[gg * 132 + t];
        atomicAdd(&st3[t], s);
    }
    __syncthreads();
#pragma unroll
    for (int j = 0; j < 8; ++j) red[g * 132 + c8 + j] = sq[j];
    __syncthreads();
    if (t < 128) {
        float s = 0;
#pragma unroll
        for (int gg = 0; gg < 16; ++gg) s += red[gg * 132 + t];
        atomicAdd(&st3[128 + t], s);
    }
}

// last layer: d[n] = (relu(bn3(Y[n])) + HIN[n]) . v ; gsum[gid[n]] += d[n]
__global__ __launch_bounds__(256) void fin_last(
    const unsigned short* __restrict__ Y, const unsigned short* __restrict__ HIN,
    const float* __restrict__ st3, const float* __restrict__ g3,
    const float* __restrict__ b3, const float* __restrict__ vvec,
    const int* __restrict__ gid, float* __restrict__ gsum)
{
    __shared__ float scb[128], shb[128];
    const int t = threadIdx.x;
    if (t < 128) {
        float m = st3[t] * INV_N;
        float va = st3[128 + t] * INV_N - m * m;
        float s = g3[t] * rsqrtf(va + 1e-5f);
        scb[t] = s; shb[t] = b3[t] - m * s;
    }
    __syncthreads();
    const int l16 = t & 15;
    const long n = (long)blockIdx.x * 16 + (t >> 4);
    const int c8 = l16 * 8;
    bf16x8 yv = *(const bf16x8*)&Y[n * HDIM + c8];
    bf16x8 hv = *(const bf16x8*)&HIN[n * HDIM + c8];
    float d = 0;
#pragma unroll
    for (int j = 0; j < 8; ++j) {
        float h = relu_f(fmaf(b2f((unsigned short)yv[j]), scb[c8 + j], shb[c8 + j]))
                  + b2f((unsigned short)hv[j]);
        d += h * vvec[c8 + j];
    }
#pragma unroll
    for (int off = 8; off > 0; off >>= 1) d += __shfl_down(d, off, 16);
    if (l16 == 0) atomicAdd(&gsum[gid[n]], d);
}

__global__ void gcnt_kernel(const int* __restrict__ gid, float* __restrict__ gcnt)
{
    int n = blockIdx.x * 256 + threadIdx.x;
    if (n < NNODES) atomicAdd(&gcnt[gid[n]], 1.0f);
}

__global__ void v_kernel(const float* __restrict__ W_ro, const float* __restrict__ W_pred,
                         float* __restrict__ v)
{
    int t = threadIdx.x;
    if (t < HDIM) {
        float s = 0;
        for (int j = 0; j < HDIM; ++j) s += W_ro[t * HDIM + j] * W_pred[j];
        v[t] = s;
    }
}

__global__ void score_kernel(const float* __restrict__ gsum, const float* __restrict__ gcnt,
                             const float* __restrict__ b_pred, float* __restrict__ out)
{
    int g = blockIdx.x * 256 + threadIdx.x;
    if (g < NGRAPH) out[g] = gsum[g] / fmaxf(gcnt[g], 1.0f) + b_pred[0];
}

extern "C" void kernel_launch(void* const* d_in, const int* in_sizes, int n_in,
                              void* d_out, int out_size, void* d_ws, size_t ws_size,
                              hipStream_t stream)
{
    const float* h_raw   = (const float*)d_in[0];
    const int*   src     = (const int*)d_in[1];
    const int*   dst     = (const int*)d_in[2];
    const int*   gid     = (const int*)d_in[3];
    const float* snorm   = (const float*)d_in[4];
    const float* W_emb   = (const float*)d_in[5];
    const float* eps_gin = (const float*)d_in[6];
    const float* W1      = (const float*)d_in[7];
    const float* b1      = (const float*)d_in[8];
    const float* bn1_g   = (const float*)d_in[9];
    const float* bn1_b   = (const float*)d_in[10];
    const float* W2      = (const float*)d_in[11];
    const float* b2      = (const float*)d_in[12];
    const float* bn2_g   = (const float*)d_in[13];
    const float* bn2_b   = (const float*)d_in[14];
    const float* bn3_g   = (const float*)d_in[15];
    const float* bn3_b   = (const float*)d_in[16];
    const float* W_ro    = (const float*)d_in[17];
    const float* W_pred  = (const float*)d_in[18];
    const float* b_pred  = (const float*)d_in[19];
    float* out = (float*)d_out;

    const size_t NH = (size_t)NNODES * HDIM;      // elements per [N,128]
    unsigned short* HIN = (unsigned short*)d_ws;
    unsigned short* Pa  = HIN + NH;
    unsigned short* Pb  = Pa + NH;
    float* Z      = (float*)(Pb + NH);
    float* statsb = Z;                  // 12 * 256
    float* gsum   = Z + 12 * 256;       // 8000
    float* gcnt   = gsum + NGRAPH;      // 8000
    float* vvec   = gcnt + NGRAPH;      // 128
    int* rowptr = (int*)(vvec + 128);          // N+1
    int* deg    = rowptr + NNODES + 1;         // N (becomes Wtb after scan1)
    int* cursor = deg + NNODES;                // N
    int* bsum   = cursor + NNODES;             // 128
    int* eidx   = bsum + 128;                  // E
    unsigned short* Wtb =
        (unsigned short*)(((uintptr_t)deg + 15) & ~(uintptr_t)15);  // 9*16384 u16

    hipMemsetAsync(Z, 0, 19072 * sizeof(float), stream);
    hipMemsetAsync(deg, 0, NNODES * sizeof(int), stream);

    gcnt_kernel<<<(NNODES + 255) / 256, 256, 0, stream>>>(gid, gcnt);
    v_kernel<<<1, 128, 0, stream>>>(W_ro, W_pred, vvec);

    // CSR build (deg consumed by scan1, then its space becomes Wtb)
    deg_kernel<<<(NEDGES + 255) / 256, 256, 0, stream>>>(dst, deg);
    scan1<<<NSCANB, 256, 0, stream>>>(deg, rowptr, bsum);
    scan2<<<1, 128, 0, stream>>>(bsum);
    scan3<<<(NNODES + 255) / 256, 256, 0, stream>>>(rowptr, bsum, cursor);
    fill_eidx<<<(NEDGES + 255) / 256, 256, 0, stream>>>(src, dst, cursor, eidx);

    // weights -> bf16 fragment-order [9][8][4][64][8]
    wconv<<<(9 * 16384) / 256, 256, 0, stream>>>(W_emb, W1, W2, Wtb);

    // embedding: HIN = bf16(h_raw @ W_emb)
    gemm_mfma<true, false, false><<<GGRID, 256, 0, stream>>>(
        h_raw, Wtb, nullptr, nullptr, nullptr, nullptr, HIN, nullptr);

    // Ping-pong Pa/Pb within each layer: every producer writes the buffer the
    // previous consumer just freed -> all gemm writes are OUT-OF-PLACE.
    unsigned short* bufs[2] = {Pa, Pb};
    int cur = 0;   // index of buffer holding the current live tensor
    for (int i = 0; i < NLAYER; ++i) {
        float* st1 = statsb + (i * 3 + 0) * 256;
        float* st2 = statsb + (i * 3 + 1) * 256;
        float* st3 = statsb + (i * 3 + 2) * 256;

        if (i == 0) {
            agg_fused<true><<<NNODES / 16, 256, 0, stream>>>(
                nullptr, HIN, nullptr, nullptr, nullptr,
                rowptr, eidx, eps_gin, 0, bufs[0]);
            cur = 0;
        } else {
            float* st3p = statsb + ((i - 1) * 3 + 2) * 256;
            agg_fused<false><<<NNODES / 16, 256, 0, stream>>>(
                bufs[cur], HIN, st3p, bn3_g + (i - 1) * HDIM, bn3_b + (i - 1) * HDIM,
                rowptr, eidx, eps_gin, i, bufs[cur ^ 1]);
            cur ^= 1;
        }

        gemm_mfma<false, false, true><<<GGRID, 256, 0, stream>>>(
            bufs[cur], Wtb + (size_t)(1 + i) * 16384, b1 + i * HDIM,
            nullptr, nullptr, nullptr, bufs[cur ^ 1], st1);
        cur ^= 1;
        gemm_mfma<false, true, true><<<GGRID, 256, 0, stream>>>(
            bufs[cur], Wtb + (size_t)(5 + i) * 16384, b2 + i * HDIM,
            st1, bn1_g + i * HDIM, bn1_b + i * HDIM, bufs[cur ^ 1], st2);
        cur ^= 1;
        x3_kernel<<<X3GRID, 256, 0, stream>>>(
            bufs[cur], st2, bn2_g + i * HDIM, bn2_b + i * HDIM, snorm, st3);
    }

    fin_last<<<NNODES / 16, 256, 0, stream>>>(
        bufs[cur], HIN, statsb + (3 * 3 + 2) * 256,
        bn3_g + 3 * HDIM, bn3_b + 3 * HDIM, vvec, gid, gsum);
    score_kernel<<<(NGRAPH + 255) / 256, 256, 0, stream>>>(gsum, gcnt, b_pred, out);
}